// Round 1
// baseline (938.152 us; speedup 1.0000x reference)
//
#include <hip/hip_runtime.h>

// Problem constants
// B=256, C=64, H=W=48, E=5, DIM=65

constexpr size_t OFF_POOLED = 0;                       // 256*256          = 65536
constexpr size_t OFF_KERN   = 65536;                   // 256*4096         = 1048576  (transposed [b][i][o])
constexpr size_t OFF_W1     = 65536 + 1048576;         // 32*64*12         = 24576
constexpr size_t OFF_W2     = OFF_W1 + 32*64*12;       // 64*32*12         = 24576
constexpr size_t OFF_W3     = OFF_W2 + 64*32*12;       // 128*64*12        = 98304
constexpr size_t OFF_H1     = OFF_W3 + 128*64*12;      // 256*32*24*24     = 4718592
constexpr size_t OFF_H2     = OFF_H1 + (size_t)256*32*24*24; // 256*64*12*12 = 2359296
// total = 8339456 floats = 33.4 MB of d_ws

__device__ __forceinline__ float sigmoidf_(float z) {
    return 1.0f / (1.0f + __expf(-z));
}

// ---------------------------------------------------------------------------
// K0: weight-norm all three conv weights into padded layout [oc][ic][12]
// ---------------------------------------------------------------------------
__global__ void k_wnorm(const float* __restrict__ v1, const float* __restrict__ g1,
                        const float* __restrict__ v2, const float* __restrict__ g2,
                        const float* __restrict__ v3, const float* __restrict__ g3,
                        float* __restrict__ ws)
{
    int bo = blockIdx.x;
    const float* v; const float* g; float* out; int IC, oc;
    if (bo < 32)       { v = v1; g = g1; out = ws + OFF_W1; oc = bo;      IC = 64; }
    else if (bo < 96)  { v = v2; g = g2; out = ws + OFF_W2; oc = bo - 32; IC = 32; }
    else               { v = v3; g = g3; out = ws + OFF_W3; oc = bo - 96; IC = 64; }
    int n = IC * 9;
    const float* vo = v + (size_t)oc * n;
    float s = 0.0f;
    for (int i = threadIdx.x; i < n; i += 256) { float xv = vo[i]; s += xv * xv; }
    __shared__ float swarp[4];
    __shared__ float sscale;
    int lane = threadIdx.x & 63, wid = threadIdx.x >> 6;
    #pragma unroll
    for (int off = 32; off; off >>= 1) s += __shfl_down(s, off);
    if (lane == 0) swarp[wid] = s;
    __syncthreads();
    if (threadIdx.x == 0) {
        float tsum = swarp[0] + swarp[1] + swarp[2] + swarp[3];
        sscale = g[oc] / sqrtf(tsum);
    }
    __syncthreads();
    float sc = sscale;
    for (int i = threadIdx.x; i < n; i += 256) {
        int ic = i / 9, k = i - ic * 9;
        out[((size_t)oc * IC + ic) * 12 + k] = vo[i] * sc;
    }
}

// ---------------------------------------------------------------------------
// K1: adaptive avg-pool 2x2 -> pooled [b][c*4 + hb*2 + wb]
// ---------------------------------------------------------------------------
__global__ void k_pool(const float* __restrict__ x, float* __restrict__ ws)
{
    int bc = blockIdx.x;                       // b*64 + c
    const float* p = x + (size_t)bc * 2304;
    float a0 = 0.f, a1 = 0.f, a2 = 0.f, a3 = 0.f;
    for (int i = threadIdx.x; i < 2304; i += 256) {
        int h = i / 48, w = i - h * 48;
        float v = p[i];
        bool hq = (h >= 24), wq = (w >= 24);
        a0 += (!hq && !wq) ? v : 0.f;
        a1 += (!hq &&  wq) ? v : 0.f;
        a2 += ( hq && !wq) ? v : 0.f;
        a3 += ( hq &&  wq) ? v : 0.f;
    }
    __shared__ float red[4][4];
    int lane = threadIdx.x & 63, wid = threadIdx.x >> 6;
    float acc[1];
    // reduce each quadrant across the wave, then across the 4 waves
    #pragma unroll
    for (int q = 0; q < 4; q++) {
        float s = (q == 0) ? a0 : (q == 1) ? a1 : (q == 2) ? a2 : a3;
        #pragma unroll
        for (int off = 32; off; off >>= 1) s += __shfl_down(s, off);
        if (lane == 0) red[q][wid] = s;
    }
    (void)acc;
    __syncthreads();
    if (threadIdx.x < 4) {
        int q = threadIdx.x;
        float s = red[q][0] + red[q][1] + red[q][2] + red[q][3];
        int b = bc >> 6, c = bc & 63;
        ws[OFF_POOLED + (size_t)b * 256 + c * 4 + q] = s * (1.0f / 576.0f);
    }
}

// ---------------------------------------------------------------------------
// K2: routing (sigmoid linear over [pooled | emb]) + expert-mixed 1x1 kern,
//     stored TRANSPOSED: ws_kern[b][i][o]
// ---------------------------------------------------------------------------
__global__ void k_route(const int* __restrict__ cluster,
                        const float* __restrict__ route_emb,
                        const float* __restrict__ route_W,
                        const float* __restrict__ route_b,
                        const float* __restrict__ expert_w,
                        float* __restrict__ ws)
{
    int b = blockIdx.x, t = threadIdx.x;
    __shared__ float feat[512];
    __shared__ float rwv[5];
    __shared__ float red[256];
    int cl = cluster[b];
    feat[t]       = ws[OFF_POOLED + (size_t)b * 256 + t];
    feat[256 + t] = route_emb[(size_t)cl * 256 + t];
    __syncthreads();
    float f0 = feat[t], f1 = feat[256 + t];
    for (int e = 0; e < 5; e++) {
        float pv = f0 * route_W[e * 512 + t] + f1 * route_W[e * 512 + 256 + t];
        red[t] = pv;
        __syncthreads();
        if (t < 128) red[t] += red[t + 128];
        __syncthreads();
        if (t < 64) {
            float s = red[t] + red[t + 64];
            #pragma unroll
            for (int off = 32; off; off >>= 1) s += __shfl_down(s, off);
            if (t == 0) rwv[e] = sigmoidf_(s + route_b[e]);
        }
        __syncthreads();
    }
    float r0 = rwv[0], r1 = rwv[1], r2 = rwv[2], r3 = rwv[3], r4 = rwv[4];
    // write kern transposed: dst j = i*64 + o ; src = o*64 + i
    for (int j = t; j < 4096; j += 256) {
        int src = ((j & 63) << 6) + (j >> 6);
        float kv = r0 * expert_w[src] + r1 * expert_w[4096 + src] +
                   r2 * expert_w[2 * 4096 + src] + r3 * expert_w[3 * 4096 + src] +
                   r4 * expert_w[4 * 4096 + src];
        ws[OFF_KERN + (size_t)b * 4096 + j] = kv;
    }
}

// ---------------------------------------------------------------------------
// F1: fused  cc(1x1 per-sample conv) + sigmoid gate + conv1(3x3,wn) + prelu
//     + maxpool2x2  ->  h1[b][32][24][24]
// Tile: 6 pre-pool output rows (halo 8 input rows) x full 48 cols.
// LDS: gated tile [64ch][8r][50c-padded] (in-place gate over staged x),
//      kernT [64i][68-padded o], cond_b copy. Total 120064 B.
// ---------------------------------------------------------------------------
__global__ void __launch_bounds__(256, 1)
k_f1(const float* __restrict__ x, const float* __restrict__ kernT_g,
     const float* __restrict__ cond_b, const float* __restrict__ w1T,
     const float* __restrict__ cb1, const float* __restrict__ a1,
     float* __restrict__ h1)
{
    extern __shared__ float lds[];
    float* glds  = lds;                    // 64*8*50 = 25600
    float* kernT = lds + 25600;            // 64*68   = 4352
    float* cbl   = lds + 25600 + 4352;     // 64
    const int t = threadIdx.x;
    const int tile = blockIdx.x;           // 0..7
    const int b = blockIdx.y;
    const int r0 = tile * 6;               // pre-pool out rows r0..r0+5

    {   // kern stage (global already [i][o]) -> LDS stride 68
        const float* src = kernT_g + (size_t)b * 4096;
        for (int j = t; j < 4096; j += 256)
            kernT[(j >> 6) * 68 + (j & 63)] = src[j];
    }
    if (t < 64) cbl[t] = cond_b[t];
    // zero padded border columns
    for (int j = t; j < 64 * 8; j += 256) {
        glds[j * 50 + 0]  = 0.0f;
        glds[j * 50 + 49] = 0.0f;
    }
    // stage x: each thread owns whole channel-columns for its positions
    for (int p = t; p < 384; p += 256) {
        int hr = p / 48, col = p - hr * 48;
        int row = r0 - 1 + hr;
        float* dst = glds + hr * 50 + 1 + col;
        if (row >= 0 && row < 48) {
            const float* src = x + (size_t)b * 147456 + row * 48 + col;
            #pragma unroll
            for (int i = 0; i < 64; i++) dst[i * 400] = src[i * 2304];
        } else {
            #pragma unroll
            for (int i = 0; i < 64; i++) dst[i * 400] = 0.0f;
        }
    }
    __syncthreads();

    // cc + gate, in place on this thread's own columns
    for (int p = t; p < 384; p += 256) {
        int hr = p / 48, col = p - hr * 48;
        int base = hr * 50 + 1 + col;
        float acc[64];
        #pragma unroll
        for (int o = 0; o < 64; o++) acc[o] = 0.0f;
        for (int i = 0; i < 64; i++) {
            float xv = glds[i * 400 + base];
            const float4* kt = (const float4*)(kernT + i * 68);
            #pragma unroll
            for (int jj = 0; jj < 16; jj++) {
                float4 k4 = kt[jj];
                acc[4 * jj + 0] += k4.x * xv;
                acc[4 * jj + 1] += k4.y * xv;
                acc[4 * jj + 2] += k4.z * xv;
                acc[4 * jj + 3] += k4.w * xv;
            }
        }
        #pragma unroll
        for (int o = 0; o < 64; o++) {
            int idx = o * 400 + base;
            float sg = sigmoidf_(acc[o] + cbl[o]);
            glds[idx] = sg * glds[idx];
        }
    }
    __syncthreads();

    // conv1 3x3 + bias + prelu + maxpool2x2
    const int oc = t >> 3, g = t & 7;      // 32 oc x 8 col-groups
    float accq[36];
    #pragma unroll
    for (int q = 0; q < 36; q++) accq[q] = 0.0f;
    const float* wp = w1T + (size_t)oc * 64 * 12;
    for (int ic = 0; ic < 64; ic++) {
        float wv[9];
        #pragma unroll
        for (int k = 0; k < 9; k++) wv[k] = wp[ic * 12 + k];
        float xv[8][8];
        const float* gb = glds + ic * 400 + 6 * g;   // padded col 6g == global col 6g-1
        #pragma unroll
        for (int hr2 = 0; hr2 < 8; hr2++) {
            #pragma unroll
            for (int jj = 0; jj < 4; jj++) {
                float2 v2 = *(const float2*)(gb + hr2 * 50 + 2 * jj);
                xv[hr2][2 * jj]     = v2.x;
                xv[hr2][2 * jj + 1] = v2.y;
            }
        }
        #pragma unroll
        for (int pr = 0; pr < 3; pr++)
            #pragma unroll
            for (int pc = 0; pc < 3; pc++)
                #pragma unroll
                for (int dy = 0; dy < 2; dy++)
                    #pragma unroll
                    for (int dx = 0; dx < 2; dx++)
                        #pragma unroll
                        for (int ky = 0; ky < 3; ky++)
                            #pragma unroll
                            for (int kx = 0; kx < 3; kx++)
                                accq[(pr * 3 + pc) * 4 + dy * 2 + dx] +=
                                    wv[ky * 3 + kx] * xv[2 * pr + dy + ky][2 * pc + dx + kx];
    }
    const float cb = cb1[oc];
    const float av = a1[0];
    #pragma unroll
    for (int pr = 0; pr < 3; pr++) {
        #pragma unroll
        for (int pc = 0; pc < 3; pc++) {
            float m = -1e30f;
            #pragma unroll
            for (int q = 0; q < 4; q++) {
                float v = accq[(pr * 3 + pc) * 4 + q] + cb;
                v = (v >= 0.0f) ? v : av * v;
                m = fmaxf(m, v);
            }
            h1[((size_t)(b * 32 + oc) * 24 + (tile * 3 + pr)) * 24 + (3 * g + pc)] = m;
        }
    }
}

// ---------------------------------------------------------------------------
// F2: conv2(3x3,wn)+prelu+maxpool  h1[b][32][24][24] -> h2[b][64][12][12]
// Whole sample in LDS: [32][26][28] padded. 93184 B.
// ---------------------------------------------------------------------------
__global__ void __launch_bounds__(256, 1)
k_f2(const float* __restrict__ h1, const float* __restrict__ w2T,
     const float* __restrict__ cb2, const float* __restrict__ a2,
     float* __restrict__ h2)
{
    extern __shared__ float lds[];         // 32*26*28 = 23296
    const int b = blockIdx.x, t = threadIdx.x;
    for (int j = t; j < 23296; j += 256) lds[j] = 0.0f;
    __syncthreads();
    for (int j = t; j < 18432; j += 256) {
        int ic = j / 576, rc = j - ic * 576;
        int r = rc / 24, c = rc - r * 24;
        lds[ic * 728 + (r + 1) * 28 + (c + 1)] = h1[(size_t)b * 18432 + j];
    }
    __syncthreads();
    const int oc = t >> 2, g = t & 3;      // 64 oc x 4 col-groups
    const float cb = cb2[oc], av = a2[0];
    const float* wp = w2T + (size_t)oc * 32 * 12;
    for (int prow = 0; prow < 12; prow++) {
        float acc[12];
        #pragma unroll
        for (int q = 0; q < 12; q++) acc[q] = 0.0f;
        for (int ic = 0; ic < 32; ic++) {
            float wv[9];
            #pragma unroll
            for (int k = 0; k < 9; k++) wv[k] = wp[ic * 12 + k];
            float xv[4][8];
            const float* gb = lds + ic * 728 + (2 * prow) * 28 + 6 * g;
            #pragma unroll
            for (int rr = 0; rr < 4; rr++) {
                #pragma unroll
                for (int jj = 0; jj < 4; jj++) {
                    float2 v2 = *(const float2*)(gb + rr * 28 + 2 * jj);
                    xv[rr][2 * jj]     = v2.x;
                    xv[rr][2 * jj + 1] = v2.y;
                }
            }
            #pragma unroll
            for (int pc = 0; pc < 3; pc++)
                #pragma unroll
                for (int dy = 0; dy < 2; dy++)
                    #pragma unroll
                    for (int dx = 0; dx < 2; dx++)
                        #pragma unroll
                        for (int ky = 0; ky < 3; ky++)
                            #pragma unroll
                            for (int kx = 0; kx < 3; kx++)
                                acc[pc * 4 + dy * 2 + dx] +=
                                    wv[ky * 3 + kx] * xv[dy + ky][2 * pc + dx + kx];
        }
        #pragma unroll
        for (int pc = 0; pc < 3; pc++) {
            float m = -1e30f;
            #pragma unroll
            for (int q = 0; q < 4; q++) {
                float v = acc[pc * 4 + q] + cb;
                v = (v >= 0.0f) ? v : av * v;
                m = fmaxf(m, v);
            }
            h2[((size_t)(b * 64 + oc) * 12 + prow) * 12 + (3 * g + pc)] = m;
        }
    }
}

// ---------------------------------------------------------------------------
// F3: conv3(3x3,wn)+prelu+maxpool + spatial mean + emb2*alpha + 3-layer MLP
//     h2[b][64][12][12] -> out[b][65]
// LDS: input [64][14][16] + reduction buffers. 59264 B.
// ---------------------------------------------------------------------------
__global__ void __launch_bounds__(256, 1)
k_f3(const float* __restrict__ h2, const float* __restrict__ w3T,
     const float* __restrict__ cb3, const float* __restrict__ a3,
     const int* __restrict__ cluster, const float* __restrict__ emb2,
     const float* __restrict__ alpha,
     const float* __restrict__ mW1, const float* __restrict__ mb1, const float* __restrict__ a4,
     const float* __restrict__ mW2, const float* __restrict__ mb2, const float* __restrict__ a5,
     const float* __restrict__ mW3, const float* __restrict__ mb3,
     float* __restrict__ out)
{
    extern __shared__ float lds[];
    float* xin = lds;            // 64*14*16 = 14336
    float* ps  = lds + 14336;    // 256
    float* hb  = lds + 14592;    // 128
    float* t1  = lds + 14720;    // 64
    float* t2  = lds + 14784;    // 32
    const int b = blockIdx.x, t = threadIdx.x;
    for (int j = t; j < 14336; j += 256) xin[j] = 0.0f;
    __syncthreads();
    for (int j = t; j < 9216; j += 256) {
        int ic = j / 144, rc = j - ic * 144;
        int r = rc / 12, c = rc - r * 12;
        xin[ic * 224 + (r + 1) * 16 + (c + 1)] = h2[(size_t)b * 9216 + j];
    }
    __syncthreads();
    const int oc = t >> 1, g = t & 1;      // 128 oc x 2 col-groups
    const float cb = cb3[oc], av = a3[0];
    const float* wp = w3T + (size_t)oc * 64 * 12;
    float partial = 0.0f;
    for (int prow = 0; prow < 6; prow++) {
        float acc[12];
        #pragma unroll
        for (int q = 0; q < 12; q++) acc[q] = 0.0f;
        for (int ic = 0; ic < 64; ic++) {
            float wv[9];
            #pragma unroll
            for (int k = 0; k < 9; k++) wv[k] = wp[ic * 12 + k];
            float xv[4][8];
            const float* gb = xin + ic * 224 + (2 * prow) * 16 + 6 * g;
            #pragma unroll
            for (int rr = 0; rr < 4; rr++) {
                #pragma unroll
                for (int jj = 0; jj < 4; jj++) {
                    float2 v2 = *(const float2*)(gb + rr * 16 + 2 * jj);
                    xv[rr][2 * jj]     = v2.x;
                    xv[rr][2 * jj + 1] = v2.y;
                }
            }
            #pragma unroll
            for (int pc = 0; pc < 3; pc++)
                #pragma unroll
                for (int dy = 0; dy < 2; dy++)
                    #pragma unroll
                    for (int dx = 0; dx < 2; dx++)
                        #pragma unroll
                        for (int ky = 0; ky < 3; ky++)
                            #pragma unroll
                            for (int kx = 0; kx < 3; kx++)
                                acc[pc * 4 + dy * 2 + dx] +=
                                    wv[ky * 3 + kx] * xv[dy + ky][2 * pc + dx + kx];
        }
        #pragma unroll
        for (int pc = 0; pc < 3; pc++) {
            float m = -1e30f;
            #pragma unroll
            for (int q = 0; q < 4; q++) {
                float v = acc[pc * 4 + q] + cb;
                v = (v >= 0.0f) ? v : av * v;
                m = fmaxf(m, v);
            }
            partial += m;
        }
    }
    ps[t] = partial;               // t == oc*2 + g
    __syncthreads();
    if (t < 128) {
        int cl = cluster[b];
        hb[t] = (ps[2 * t] + ps[2 * t + 1]) * (1.0f / 36.0f)
              + emb2[(size_t)cl * 128 + t] * alpha[0];
    }
    __syncthreads();
    if (t < 64) {
        float s = mb1[t];
        #pragma unroll 4
        for (int j = 0; j < 128; j++) s += mW1[t * 128 + j] * hb[j];
        float a4v = a4[0];
        t1[t] = (s >= 0.0f) ? s : a4v * s;
    }
    __syncthreads();
    if (t < 32) {
        float s = mb2[t];
        #pragma unroll 4
        for (int j = 0; j < 64; j++) s += mW2[t * 64 + j] * t1[j];
        float a5v = a5[0];
        t2[t] = (s >= 0.0f) ? s : a5v * s;
    }
    __syncthreads();
    if (t < 65) {
        float s = mb3[t];
        #pragma unroll 4
        for (int j = 0; j < 32; j++) s += mW3[t * 32 + j] * t2[j];
        out[(size_t)b * 65 + t] = s;
    }
}

// ---------------------------------------------------------------------------
extern "C" void kernel_launch(void* const* d_in, const int* in_sizes, int n_in,
                              void* d_out, int out_size, void* d_ws, size_t ws_size,
                              hipStream_t stream)
{
    const float* x         = (const float*)d_in[0];
    const int*   cluster   = (const int*)  d_in[1];
    const float* expert_w  = (const float*)d_in[2];
    const float* cond_b    = (const float*)d_in[3];
    const float* route_emb = (const float*)d_in[4];
    const float* route_W   = (const float*)d_in[5];
    const float* route_b   = (const float*)d_in[6];
    const float* v1  = (const float*)d_in[7];
    const float* g1  = (const float*)d_in[8];
    const float* cb1 = (const float*)d_in[9];
    const float* a1  = (const float*)d_in[10];
    const float* v2  = (const float*)d_in[11];
    const float* g2  = (const float*)d_in[12];
    const float* cb2 = (const float*)d_in[13];
    const float* a2  = (const float*)d_in[14];
    const float* v3  = (const float*)d_in[15];
    const float* g3  = (const float*)d_in[16];
    const float* cb3 = (const float*)d_in[17];
    const float* a3  = (const float*)d_in[18];
    const float* emb2  = (const float*)d_in[19];
    const float* alpha = (const float*)d_in[20];
    const float* mW1 = (const float*)d_in[21];
    const float* mb1 = (const float*)d_in[22];
    const float* a4  = (const float*)d_in[23];
    const float* mW2 = (const float*)d_in[24];
    const float* mb2 = (const float*)d_in[25];
    const float* a5  = (const float*)d_in[26];
    const float* mW3 = (const float*)d_in[27];
    const float* mb3 = (const float*)d_in[28];
    float* ws  = (float*)d_ws;
    float* out = (float*)d_out;

    // allow >64KB dynamic LDS (gfx950 supports up to 160KB/workgroup)
    hipFuncSetAttribute((const void*)k_f1, hipFuncAttributeMaxDynamicSharedMemorySize, 120064);
    hipFuncSetAttribute((const void*)k_f2, hipFuncAttributeMaxDynamicSharedMemorySize, 93184);
    hipFuncSetAttribute((const void*)k_f3, hipFuncAttributeMaxDynamicSharedMemorySize, 59264);

    k_wnorm<<<224, 256, 0, stream>>>(v1, g1, v2, g2, v3, g3, ws);
    k_pool<<<16384, 256, 0, stream>>>(x, ws);
    k_route<<<256, 256, 0, stream>>>(cluster, route_emb, route_W, route_b, expert_w, ws);
    k_f1<<<dim3(8, 256), 256, 120064, stream>>>(x, ws + OFF_KERN, cond_b,
                                                ws + OFF_W1, cb1, a1, ws + OFF_H1);
    k_f2<<<256, 256, 93184, stream>>>(ws + OFF_H1, ws + OFF_W2, cb2, a2, ws + OFF_H2);
    k_f3<<<256, 256, 59264, stream>>>(ws + OFF_H2, ws + OFF_W3, cb3, a3,
                                      cluster, emb2, alpha,
                                      mW1, mb1, a4, mW2, mb2, a5, mW3, mb3, out);
}

// Round 2
// 409.027 us; speedup vs baseline: 2.2936x; 2.2936x over previous
//
#include <hip/hip_runtime.h>

// Problem constants: B=256, C=64, H=W=48, E=5, DIM=65

typedef _Float16 f16;
typedef f16 f16x8 __attribute__((ext_vector_type(8)));
typedef f16 f16x4 __attribute__((ext_vector_type(4)));
typedef float f32x4 __attribute__((ext_vector_type(4)));

constexpr size_t OFF_POOLED = 0;                       // 256*256 f32
constexpr size_t OFF_KERN   = 65536;                   // region holds 256*4096 f16 (kernH, swizzled [o][i])
constexpr size_t OFF_W1     = 65536 + 1048576;         // region holds 9*32*64 f16 (w1H, swizzled [kk][oc][ic])
constexpr size_t OFF_W2     = OFF_W1 + 32*64*12;       // 64*32*12 f32
constexpr size_t OFF_W3     = OFF_W2 + 64*32*12;       // 128*64*12 f32
constexpr size_t OFF_H1     = OFF_W3 + 128*64*12;      // 256*32*24*24 f32
constexpr size_t OFF_H2     = OFF_H1 + (size_t)256*32*24*24; // 256*64*12*12 f32

__device__ __forceinline__ float sigmoidf_(float z) {
    return 1.0f / (1.0f + __expf(-z));
}

// ---------------------------------------------------------------------------
// K0: weight-norm. w1 -> fp16 swizzled [kk][oc][ic^((oc&7)<<3)]; w2/w3 fp32 [oc][ic][12]
// ---------------------------------------------------------------------------
__global__ void k_wnorm(const float* __restrict__ v1, const float* __restrict__ g1,
                        const float* __restrict__ v2, const float* __restrict__ g2,
                        const float* __restrict__ v3, const float* __restrict__ g3,
                        float* __restrict__ ws)
{
    int bo = blockIdx.x;
    const float* v; const float* g; int IC, oc; int which;
    if (bo < 32)       { v = v1; g = g1; oc = bo;      IC = 64; which = 1; }
    else if (bo < 96)  { v = v2; g = g2; oc = bo - 32; IC = 32; which = 2; }
    else               { v = v3; g = g3; oc = bo - 96; IC = 64; which = 3; }
    int n = IC * 9;
    const float* vo = v + (size_t)oc * n;
    float s = 0.0f;
    for (int i = threadIdx.x; i < n; i += 256) { float xv = vo[i]; s += xv * xv; }
    __shared__ float swarp[4];
    __shared__ float sscale;
    int lane = threadIdx.x & 63, wid = threadIdx.x >> 6;
    #pragma unroll
    for (int off = 32; off; off >>= 1) s += __shfl_down(s, off);
    if (lane == 0) swarp[wid] = s;
    __syncthreads();
    if (threadIdx.x == 0) {
        float tsum = swarp[0] + swarp[1] + swarp[2] + swarp[3];
        sscale = g[oc] / sqrtf(tsum);
    }
    __syncthreads();
    float sc = sscale;
    if (which == 1) {
        f16* o1 = (f16*)(ws + OFF_W1);
        for (int i = threadIdx.x; i < n; i += 256) {
            int ic = i / 9, kk = i - ic * 9;
            o1[kk * 2048 + oc * 64 + (ic ^ ((oc & 7) << 3))] = (f16)(vo[i] * sc);
        }
    } else {
        float* out = ws + (which == 2 ? OFF_W2 : OFF_W3);
        for (int i = threadIdx.x; i < n; i += 256) {
            int ic = i / 9, k = i - ic * 9;
            out[((size_t)oc * IC + ic) * 12 + k] = vo[i] * sc;
        }
    }
}

// ---------------------------------------------------------------------------
// K1: adaptive avg-pool 2x2 -> pooled [b][c*4 + hb*2 + wb]
// ---------------------------------------------------------------------------
__global__ void k_pool(const float* __restrict__ x, float* __restrict__ ws)
{
    int bc = blockIdx.x;
    const float* p = x + (size_t)bc * 2304;
    float a0 = 0.f, a1 = 0.f, a2 = 0.f, a3 = 0.f;
    for (int i = threadIdx.x; i < 2304; i += 256) {
        int h = i / 48, w = i - h * 48;
        float v = p[i];
        bool hq = (h >= 24), wq = (w >= 24);
        a0 += (!hq && !wq) ? v : 0.f;
        a1 += (!hq &&  wq) ? v : 0.f;
        a2 += ( hq && !wq) ? v : 0.f;
        a3 += ( hq &&  wq) ? v : 0.f;
    }
    __shared__ float red[4][4];
    int lane = threadIdx.x & 63, wid = threadIdx.x >> 6;
    #pragma unroll
    for (int q = 0; q < 4; q++) {
        float s = (q == 0) ? a0 : (q == 1) ? a1 : (q == 2) ? a2 : a3;
        #pragma unroll
        for (int off = 32; off; off >>= 1) s += __shfl_down(s, off);
        if (lane == 0) red[q][wid] = s;
    }
    __syncthreads();
    if (threadIdx.x < 4) {
        int q = threadIdx.x;
        float s = red[q][0] + red[q][1] + red[q][2] + red[q][3];
        int b = bc >> 6, c = bc & 63;
        ws[OFF_POOLED + (size_t)b * 256 + c * 4 + q] = s * (1.0f / 576.0f);
    }
}

// ---------------------------------------------------------------------------
// K2: routing + expert-mixed 1x1 kern -> fp16 swizzled [b][oc][ic^((oc&7)<<3)]
// ---------------------------------------------------------------------------
__global__ void k_route(const int* __restrict__ cluster,
                        const float* __restrict__ route_emb,
                        const float* __restrict__ route_W,
                        const float* __restrict__ route_b,
                        const float* __restrict__ expert_w,
                        float* __restrict__ ws)
{
    int b = blockIdx.x, t = threadIdx.x;
    __shared__ float feat[512];
    __shared__ float rwv[5];
    __shared__ float red[256];
    int cl = cluster[b];
    feat[t]       = ws[OFF_POOLED + (size_t)b * 256 + t];
    feat[256 + t] = route_emb[(size_t)cl * 256 + t];
    __syncthreads();
    float f0 = feat[t], f1 = feat[256 + t];
    for (int e = 0; e < 5; e++) {
        float pv = f0 * route_W[e * 512 + t] + f1 * route_W[e * 512 + 256 + t];
        red[t] = pv;
        __syncthreads();
        if (t < 128) red[t] += red[t + 128];
        __syncthreads();
        if (t < 64) {
            float s = red[t] + red[t + 64];
            #pragma unroll
            for (int off = 32; off; off >>= 1) s += __shfl_down(s, off);
            if (t == 0) rwv[e] = sigmoidf_(s + route_b[e]);
        }
        __syncthreads();
    }
    float r0 = rwv[0], r1 = rwv[1], r2 = rwv[2], r3 = rwv[3], r4 = rwv[4];
    f16* khg = (f16*)(ws + OFF_KERN);
    for (int j = t; j < 4096; j += 256) {
        int oc = j >> 6, ic = j & 63;
        float kv = r0 * expert_w[j] + r1 * expert_w[4096 + j] +
                   r2 * expert_w[2 * 4096 + j] + r3 * expert_w[3 * 4096 + j] +
                   r4 * expert_w[4 * 4096 + j];
        khg[(size_t)b * 4096 + oc * 64 + (ic ^ ((oc & 7) << 3))] = (f16)kv;
    }
}

// ---------------------------------------------------------------------------
// F1 (MFMA): cc(1x1) + sigmoid gate + conv1(3x3) + prelu + maxpool -> h1
// 512 threads / 8 waves; tile = 8 out rows x 48 cols; 6 tiles per sample.
// LDS: glds fp16 [10 rows][50 cols][72-stride, 64ic swizzled ic^((col&7)<<3)]
//      + w1 fp16 [9][32][64 swz] + kern fp16 [64][64 swz] + cond_b.
// ---------------------------------------------------------------------------
__global__ void __launch_bounds__(512, 2)
k_f1(const float* __restrict__ x, const f16* __restrict__ kernH,
     const float* __restrict__ cond_b, const f16* __restrict__ w1H,
     const float* __restrict__ cb1, const float* __restrict__ a1,
     float* __restrict__ h1)
{
    extern __shared__ char smem[];
    f16* glds = (f16*)smem;                 // 10*50*72 = 36000 halves
    f16* wl   = glds + 36000;               // 18432 halves
    f16* kh   = wl + 18432;                 // 4096 halves
    float* cbl = (float*)(kh + 4096);       // 64 f32
    float* dump = (float*)smem;             // overlay: 384*34 f32 = 52224B

    const int t = threadIdx.x;
    const int tile = blockIdx.x;            // 0..5
    const int b = blockIdx.y;
    const int r0 = tile * 8;
    const int w = t >> 6, l = t & 63;
    const int l15 = l & 15, agrp = l >> 4;

    // ---- phase 0a: zero glds ----
    {
        uint4 z; z.x = z.y = z.z = z.w = 0u;
        for (int e = t; e < 4500; e += 512) *(uint4*)&glds[e * 8] = z;
    }
    __syncthreads();
    // ---- phase 0b: stage weights, kern, cond_b, and x (fp16 channel-last swizzled) ----
    for (int e = t; e < 2304; e += 512) ((uint4*)wl)[e] = ((const uint4*)w1H)[e];
    ((uint4*)kh)[t & 511] = ((const uint4*)(kernH + (size_t)b * 4096))[t & 511];
    if (t < 64) cbl[t] = cond_b[t];
    for (int e = t; e < 7680; e += 512) {
        int ig = e / 480;
        int pos = e - ig * 480;
        int i = ig * 4;
        int srow = pos / 48, scl = pos - srow * 48;
        int r_in = r0 - 1 + srow;
        if (r_in >= 0 && r_in < 48) {
            const float* xp = x + (((size_t)b * 64 + i) * 48 + r_in) * 48 + scl;
            float v0 = xp[0], v1_ = xp[2304], v2_ = xp[4608], v3_ = xp[6912];
            int sc = scl + 1;
            int ix = i ^ ((sc & 7) << 3);
            f16x4 hv = { (f16)v0, (f16)v1_, (f16)v2_, (f16)v3_ };
            *(f16x4*)&glds[(srow * 50 + sc) * 72 + ix] = hv;
        }
    }
    __syncthreads();

    // ---- phase 1: cc 1x1 conv via MFMA, gate in place ----
    {
        const int mt0 = (w < 6) ? 4 * w : 24 + 3 * (w - 6);
        const int nmt = (w < 6) ? 4 : 3;
        f32x4 acc[4][4] = {};
        int prow[4], pcol[4];
        #pragma unroll
        for (int mi = 0; mi < 4; mi++) {
            int p = (mt0 + mi) * 16 + l15;
            prow[mi] = p / 48; pcol[mi] = p - prow[mi] * 48 + 1;
        }
        #pragma unroll
        for (int ks = 0; ks < 2; ks++) {
            f16x8 bfr[4];
            #pragma unroll
            for (int nt = 0; nt < 4; nt++) {
                int oc = nt * 16 + l15;
                int slot = (ks * 4 + agrp) ^ (oc & 7);
                bfr[nt] = *(const f16x8*)&kh[oc * 64 + slot * 8];
            }
            f16x8 afr[4];
            #pragma unroll
            for (int mi = 0; mi < 4; mi++) {
                if (mi < nmt) {
                    int slot = (ks * 4 + agrp) ^ (pcol[mi] & 7);
                    afr[mi] = *(const f16x8*)&glds[(prow[mi] * 50 + pcol[mi]) * 72 + slot * 8];
                }
            }
            #pragma unroll
            for (int mi = 0; mi < 4; mi++)
                if (mi < nmt) {
                    #pragma unroll
                    for (int nt = 0; nt < 4; nt++)
                        acc[mi][nt] = __builtin_amdgcn_mfma_f32_16x16x32_f16(afr[mi], bfr[nt], acc[mi][nt], 0, 0, 0);
                }
        }
        // gate epilogue: gated = sigmoid(acc + cond_b) * x, written back in place (fp16)
        #pragma unroll
        for (int mi = 0; mi < 4; mi++) {
            if (mi < nmt) {
                #pragma unroll
                for (int nt = 0; nt < 4; nt++) {
                    int oc = nt * 16 + l15;
                    float cb = cbl[oc];
                    #pragma unroll
                    for (int r = 0; r < 4; r++) {
                        int p = (mt0 + mi) * 16 + 4 * agrp + r;
                        int sr = p / 48; int sc = p - sr * 48 + 1;
                        int addr = (sr * 50 + sc) * 72 + (oc ^ ((sc & 7) << 3));
                        float xv = (float)glds[addr];
                        float g = sigmoidf_(acc[mi][nt][r] + cb);
                        glds[addr] = (f16)(g * xv);
                    }
                }
            }
        }
    }
    __syncthreads();

    // ---- phase 2: conv1 3x3 via MFMA (K = 9 taps x 64 ic) ----
    f32x4 c2[3][2] = {};
    {
        const int q = w;   // out row
        #pragma unroll
        for (int kt = 0; kt < 18; kt++) {
            const int kk = kt >> 1, hh = kt & 1;
            const int dy = kk / 3, dx = kk - dy * 3;
            f16x8 bfr2[2];
            #pragma unroll
            for (int nt = 0; nt < 2; nt++) {
                int oc = nt * 16 + l15;
                int slot = (hh * 4 + agrp) ^ (oc & 7);
                bfr2[nt] = *(const f16x8*)&wl[(kk * 32 + oc) * 64 + slot * 8];
            }
            #pragma unroll
            for (int mtl = 0; mtl < 3; mtl++) {
                int c = mtl * 16 + l15;
                int sc = c + dx;
                int slot = (hh * 4 + agrp) ^ (sc & 7);
                f16x8 af = *(const f16x8*)&glds[((q + dy) * 50 + sc) * 72 + slot * 8];
                c2[mtl][0] = __builtin_amdgcn_mfma_f32_16x16x32_f16(af, bfr2[0], c2[mtl][0], 0, 0, 0);
                c2[mtl][1] = __builtin_amdgcn_mfma_f32_16x16x32_f16(af, bfr2[1], c2[mtl][1], 0, 0, 0);
            }
        }
    }
    __syncthreads();   // glds reads done; dump overlays

    // ---- phase 3: dump raw conv acc to LDS [pos][34-stride oc] ----
    {
        const int q = w;
        #pragma unroll
        for (int mtl = 0; mtl < 3; mtl++)
            #pragma unroll
            for (int nt = 0; nt < 2; nt++)
                #pragma unroll
                for (int r = 0; r < 4; r++) {
                    int pcl = mtl * 16 + 4 * agrp + r;
                    dump[(q * 48 + pcl) * 34 + nt * 16 + l15] = c2[mtl][nt][r];
                }
    }
    __syncthreads();

    // ---- phase 4: maxpool 2x2 + bias + prelu -> h1 ----
    {
        const float av = a1[0];
        #pragma unroll
        for (int k = 0; k < 6; k++) {
            int o2 = t + 512 * k;
            int pc = o2 % 24;
            int tmp = o2 / 24;
            int pr = tmp & 3;
            int oc = tmp >> 2;
            int base = ((2 * pr) * 48 + 2 * pc) * 34 + oc;
            float m = fmaxf(fmaxf(dump[base], dump[base + 34]),
                            fmaxf(dump[base + 48 * 34], dump[base + 48 * 34 + 34]));
            float v = m + cb1[oc];
            v = (v >= 0.0f) ? v : av * v;
            h1[((size_t)(b * 32 + oc) * 24 + (tile * 4 + pr)) * 24 + pc] = v;
        }
    }
}

// ---------------------------------------------------------------------------
// F2: conv2(3x3,wn)+prelu+maxpool  h1[b][32][24][24] -> h2[b][64][12][12]
// ---------------------------------------------------------------------------
__global__ void __launch_bounds__(256, 1)
k_f2(const float* __restrict__ h1, const float* __restrict__ w2T,
     const float* __restrict__ cb2, const float* __restrict__ a2,
     float* __restrict__ h2)
{
    extern __shared__ float lds[];
    const int b = blockIdx.x, t = threadIdx.x;
    for (int j = t; j < 23296; j += 256) lds[j] = 0.0f;
    __syncthreads();
    for (int j = t; j < 18432; j += 256) {
        int ic = j / 576, rc = j - ic * 576;
        int r = rc / 24, c = rc - r * 24;
        lds[ic * 728 + (r + 1) * 28 + (c + 1)] = h1[(size_t)b * 18432 + j];
    }
    __syncthreads();
    const int oc = t >> 2, g = t & 3;
    const float cb = cb2[oc], av = a2[0];
    const float* wp = w2T + (size_t)oc * 32 * 12;
    for (int prow = 0; prow < 12; prow++) {
        float acc[12];
        #pragma unroll
        for (int q = 0; q < 12; q++) acc[q] = 0.0f;
        for (int ic = 0; ic < 32; ic++) {
            float wv[9];
            #pragma unroll
            for (int k = 0; k < 9; k++) wv[k] = wp[ic * 12 + k];
            float xv[4][8];
            const float* gb = lds + ic * 728 + (2 * prow) * 28 + 6 * g;
            #pragma unroll
            for (int rr = 0; rr < 4; rr++) {
                #pragma unroll
                for (int jj = 0; jj < 4; jj++) {
                    float2 v2 = *(const float2*)(gb + rr * 28 + 2 * jj);
                    xv[rr][2 * jj]     = v2.x;
                    xv[rr][2 * jj + 1] = v2.y;
                }
            }
            #pragma unroll
            for (int pc = 0; pc < 3; pc++)
                #pragma unroll
                for (int dy = 0; dy < 2; dy++)
                    #pragma unroll
                    for (int dx = 0; dx < 2; dx++)
                        #pragma unroll
                        for (int ky = 0; ky < 3; ky++)
                            #pragma unroll
                            for (int kx = 0; kx < 3; kx++)
                                acc[pc * 4 + dy * 2 + dx] +=
                                    wv[ky * 3 + kx] * xv[dy + ky][2 * pc + dx + kx];
        }
        #pragma unroll
        for (int pc = 0; pc < 3; pc++) {
            float m = -1e30f;
            #pragma unroll
            for (int q = 0; q < 4; q++) {
                float v = acc[pc * 4 + q] + cb;
                v = (v >= 0.0f) ? v : av * v;
                m = fmaxf(m, v);
            }
            h2[((size_t)(b * 64 + oc) * 12 + prow) * 12 + (3 * g + pc)] = m;
        }
    }
}

// ---------------------------------------------------------------------------
// F3: conv3(3x3,wn)+prelu+maxpool + mean + emb2*alpha + MLP -> out[b][65]
// ---------------------------------------------------------------------------
__global__ void __launch_bounds__(256, 1)
k_f3(const float* __restrict__ h2, const float* __restrict__ w3T,
     const float* __restrict__ cb3, const float* __restrict__ a3,
     const int* __restrict__ cluster, const float* __restrict__ emb2,
     const float* __restrict__ alpha,
     const float* __restrict__ mW1, const float* __restrict__ mb1, const float* __restrict__ a4,
     const float* __restrict__ mW2, const float* __restrict__ mb2, const float* __restrict__ a5,
     const float* __restrict__ mW3, const float* __restrict__ mb3,
     float* __restrict__ out)
{
    extern __shared__ float lds[];
    float* xin = lds;
    float* ps  = lds + 14336;
    float* hb  = lds + 14592;
    float* t1  = lds + 14720;
    float* t2  = lds + 14784;
    const int b = blockIdx.x, t = threadIdx.x;
    for (int j = t; j < 14336; j += 256) xin[j] = 0.0f;
    __syncthreads();
    for (int j = t; j < 9216; j += 256) {
        int ic = j / 144, rc = j - ic * 144;
        int r = rc / 12, c = rc - r * 12;
        xin[ic * 224 + (r + 1) * 16 + (c + 1)] = h2[(size_t)b * 9216 + j];
    }
    __syncthreads();
    const int oc = t >> 1, g = t & 1;
    const float cb = cb3[oc], av = a3[0];
    const float* wp = w3T + (size_t)oc * 64 * 12;
    float partial = 0.0f;
    for (int prow = 0; prow < 6; prow++) {
        float acc[12];
        #pragma unroll
        for (int q = 0; q < 12; q++) acc[q] = 0.0f;
        for (int ic = 0; ic < 64; ic++) {
            float wv[9];
            #pragma unroll
            for (int k = 0; k < 9; k++) wv[k] = wp[ic * 12 + k];
            float xv[4][8];
            const float* gb = xin + ic * 224 + (2 * prow) * 16 + 6 * g;
            #pragma unroll
            for (int rr = 0; rr < 4; rr++) {
                #pragma unroll
                for (int jj = 0; jj < 4; jj++) {
                    float2 v2 = *(const float2*)(gb + rr * 16 + 2 * jj);
                    xv[rr][2 * jj]     = v2.x;
                    xv[rr][2 * jj + 1] = v2.y;
                }
            }
            #pragma unroll
            for (int pc = 0; pc < 3; pc++)
                #pragma unroll
                for (int dy = 0; dy < 2; dy++)
                    #pragma unroll
                    for (int dx = 0; dx < 2; dx++)
                        #pragma unroll
                        for (int ky = 0; ky < 3; ky++)
                            #pragma unroll
                            for (int kx = 0; kx < 3; kx++)
                                acc[pc * 4 + dy * 2 + dx] +=
                                    wv[ky * 3 + kx] * xv[dy + ky][2 * pc + dx + kx];
        }
        #pragma unroll
        for (int pc = 0; pc < 3; pc++) {
            float m = -1e30f;
            #pragma unroll
            for (int q = 0; q < 4; q++) {
                float v = acc[pc * 4 + q] + cb;
                v = (v >= 0.0f) ? v : av * v;
                m = fmaxf(m, v);
            }
            partial += m;
        }
    }
    ps[t] = partial;
    __syncthreads();
    if (t < 128) {
        int cl = cluster[b];
        hb[t] = (ps[2 * t] + ps[2 * t + 1]) * (1.0f / 36.0f)
              + emb2[(size_t)cl * 128 + t] * alpha[0];
    }
    __syncthreads();
    if (t < 64) {
        float s = mb1[t];
        #pragma unroll 4
        for (int j = 0; j < 128; j++) s += mW1[t * 128 + j] * hb[j];
        float a4v = a4[0];
        t1[t] = (s >= 0.0f) ? s : a4v * s;
    }
    __syncthreads();
    if (t < 32) {
        float s = mb2[t];
        #pragma unroll 4
        for (int j = 0; j < 64; j++) s += mW2[t * 64 + j] * t1[j];
        float a5v = a5[0];
        t2[t] = (s >= 0.0f) ? s : a5v * s;
    }
    __syncthreads();
    if (t < 65) {
        float s = mb3[t];
        #pragma unroll 4
        for (int j = 0; j < 32; j++) s += mW3[t * 32 + j] * t2[j];
        out[(size_t)b * 65 + t] = s;
    }
}

// ---------------------------------------------------------------------------
extern "C" void kernel_launch(void* const* d_in, const int* in_sizes, int n_in,
                              void* d_out, int out_size, void* d_ws, size_t ws_size,
                              hipStream_t stream)
{
    const float* x         = (const float*)d_in[0];
    const int*   cluster   = (const int*)  d_in[1];
    const float* expert_w  = (const float*)d_in[2];
    const float* cond_b    = (const float*)d_in[3];
    const float* route_emb = (const float*)d_in[4];
    const float* route_W   = (const float*)d_in[5];
    const float* route_b   = (const float*)d_in[6];
    const float* v1  = (const float*)d_in[7];
    const float* g1  = (const float*)d_in[8];
    const float* cb1 = (const float*)d_in[9];
    const float* a1  = (const float*)d_in[10];
    const float* v2  = (const float*)d_in[11];
    const float* g2  = (const float*)d_in[12];
    const float* cb2 = (const float*)d_in[13];
    const float* a2  = (const float*)d_in[14];
    const float* v3  = (const float*)d_in[15];
    const float* g3  = (const float*)d_in[16];
    const float* cb3 = (const float*)d_in[17];
    const float* a3  = (const float*)d_in[18];
    const float* emb2  = (const float*)d_in[19];
    const float* alpha = (const float*)d_in[20];
    const float* mW1 = (const float*)d_in[21];
    const float* mb1 = (const float*)d_in[22];
    const float* a4  = (const float*)d_in[23];
    const float* mW2 = (const float*)d_in[24];
    const float* mb2 = (const float*)d_in[25];
    const float* a5  = (const float*)d_in[26];
    const float* mW3 = (const float*)d_in[27];
    const float* mb3 = (const float*)d_in[28];
    float* ws  = (float*)d_ws;
    float* out = (float*)d_out;

    hipFuncSetAttribute((const void*)k_f1, hipFuncAttributeMaxDynamicSharedMemorySize, 117312);
    hipFuncSetAttribute((const void*)k_f2, hipFuncAttributeMaxDynamicSharedMemorySize, 93184);
    hipFuncSetAttribute((const void*)k_f3, hipFuncAttributeMaxDynamicSharedMemorySize, 59264);

    k_wnorm<<<224, 256, 0, stream>>>(v1, g1, v2, g2, v3, g3, ws);
    k_pool<<<16384, 256, 0, stream>>>(x, ws);
    k_route<<<256, 256, 0, stream>>>(cluster, route_emb, route_W, route_b, expert_w, ws);
    k_f1<<<dim3(6, 256), 512, 117312, stream>>>(x, (const f16*)(ws + OFF_KERN), cond_b,
                                                (const f16*)(ws + OFF_W1), cb1, a1, ws + OFF_H1);
    k_f2<<<256, 256, 93184, stream>>>(ws + OFF_H1, ws + OFF_W2, cb2, a2, ws + OFF_H2);
    k_f3<<<256, 256, 59264, stream>>>(ws + OFF_H2, ws + OFF_W3, cb3, a3,
                                      cluster, emb2, alpha,
                                      mW1, mb1, a4, mW2, mb2, a5, mW3, mb3, out);
}

// Round 3
// 182.769 us; speedup vs baseline: 5.1330x; 2.2379x over previous
//
#include <hip/hip_runtime.h>

// Problem constants: B=256, C=64, H=W=48, E=5, DIM=65

typedef _Float16 f16;
typedef f16 f16x8 __attribute__((ext_vector_type(8)));
typedef f16 f16x4 __attribute__((ext_vector_type(4)));
typedef f16 f16x2 __attribute__((ext_vector_type(2)));
typedef float f32x4 __attribute__((ext_vector_type(4)));

constexpr size_t OFF_POOLED = 0;                       // 256*256 f32
constexpr size_t OFF_KERN   = 65536;                   // 256*4096 f16 (swizzled [b][oc][ic^((oc&7)<<3)])
constexpr size_t OFF_W1     = 65536 + 1048576;         // 9*32*64 f16 swizzled [kk][oc][ic^((oc&7)<<3)]
constexpr size_t OFF_W2     = OFF_W1 + 32*64*12;       // 9*64*32 f16 linear [kk][oc][ic]
constexpr size_t OFF_W3     = OFF_W2 + 64*32*12;       // 9*128*64 f16 linear [kk][oc][ic]
constexpr size_t OFF_H1     = OFF_W3 + 128*64*12;      // 256*576*32 f16 channel-last [b][pos][ic]

__device__ __forceinline__ float sigmoidf_(float z) {
    return 1.0f / (1.0f + __expf(-z));
}

// ---------------------------------------------------------------------------
// K0: weight-norm.
//  w1 -> fp16 swizzled [kk][32 oc][64 ic ^ ((oc&7)<<3)]
//  w2 -> fp16 linear  [kk][64 oc][32 ic]
//  w3 -> fp16 linear  [kk][128 oc][64 ic]
// ---------------------------------------------------------------------------
__global__ void k_wnorm(const float* __restrict__ v1, const float* __restrict__ g1,
                        const float* __restrict__ v2, const float* __restrict__ g2,
                        const float* __restrict__ v3, const float* __restrict__ g3,
                        float* __restrict__ ws)
{
    int bo = blockIdx.x;
    const float* v; const float* g; int IC, oc; int which;
    if (bo < 32)       { v = v1; g = g1; oc = bo;      IC = 64; which = 1; }
    else if (bo < 96)  { v = v2; g = g2; oc = bo - 32; IC = 32; which = 2; }
    else               { v = v3; g = g3; oc = bo - 96; IC = 64; which = 3; }
    int n = IC * 9;
    const float* vo = v + (size_t)oc * n;
    float s = 0.0f;
    for (int i = threadIdx.x; i < n; i += 256) { float xv = vo[i]; s += xv * xv; }
    __shared__ float swarp[4];
    __shared__ float sscale;
    int lane = threadIdx.x & 63, wid = threadIdx.x >> 6;
    #pragma unroll
    for (int off = 32; off; off >>= 1) s += __shfl_down(s, off);
    if (lane == 0) swarp[wid] = s;
    __syncthreads();
    if (threadIdx.x == 0) {
        float tsum = swarp[0] + swarp[1] + swarp[2] + swarp[3];
        sscale = g[oc] / sqrtf(tsum);
    }
    __syncthreads();
    float sc = sscale;
    if (which == 1) {
        f16* o1 = (f16*)(ws + OFF_W1);
        for (int i = threadIdx.x; i < n; i += 256) {
            int ic = i / 9, kk = i - ic * 9;
            o1[kk * 2048 + oc * 64 + (ic ^ ((oc & 7) << 3))] = (f16)(vo[i] * sc);
        }
    } else if (which == 2) {
        f16* o2 = (f16*)(ws + OFF_W2);
        for (int i = threadIdx.x; i < n; i += 256) {
            int ic = i / 9, kk = i - ic * 9;
            o2[(kk * 64 + oc) * 32 + ic] = (f16)(vo[i] * sc);
        }
    } else {
        f16* o3 = (f16*)(ws + OFF_W3);
        for (int i = threadIdx.x; i < n; i += 256) {
            int ic = i / 9, kk = i - ic * 9;
            o3[(kk * 128 + oc) * 64 + ic] = (f16)(vo[i] * sc);
        }
    }
}

// ---------------------------------------------------------------------------
// K1: adaptive avg-pool 2x2, one wave per (b,c) slab, float4 loads
// ---------------------------------------------------------------------------
__global__ void __launch_bounds__(64)
k_pool(const float* __restrict__ x, float* __restrict__ ws)
{
    int bc = blockIdx.x;
    int lane = threadIdx.x;
    const float4* p = (const float4*)(x + (size_t)bc * 2304);
    float a0 = 0.f, a1 = 0.f, a2 = 0.f, a3 = 0.f;
    #pragma unroll
    for (int j = 0; j < 9; j++) {
        int i = lane + 64 * j;            // < 576
        int row = i / 12, cg = i - 12 * row;
        float4 v = p[i];
        float s = v.x + v.y + v.z + v.w;
        bool hq = (row >= 24), wq = (cg >= 6);
        a0 += (!hq && !wq) ? s : 0.f;
        a1 += (!hq &&  wq) ? s : 0.f;
        a2 += ( hq && !wq) ? s : 0.f;
        a3 += ( hq &&  wq) ? s : 0.f;
    }
    #pragma unroll
    for (int off = 32; off; off >>= 1) {
        a0 += __shfl_down(a0, off);
        a1 += __shfl_down(a1, off);
        a2 += __shfl_down(a2, off);
        a3 += __shfl_down(a3, off);
    }
    if (lane == 0) {
        int b = bc >> 6, c = bc & 63;
        float* d = ws + OFF_POOLED + (size_t)b * 256 + c * 4;
        d[0] = a0 * (1.0f / 576.0f);
        d[1] = a1 * (1.0f / 576.0f);
        d[2] = a2 * (1.0f / 576.0f);
        d[3] = a3 * (1.0f / 576.0f);
    }
}

// ---------------------------------------------------------------------------
// K2: routing + expert-mixed 1x1 kern -> fp16 swizzled [b][oc][ic^((oc&7)<<3)]
// ---------------------------------------------------------------------------
__global__ void k_route(const int* __restrict__ cluster,
                        const float* __restrict__ route_emb,
                        const float* __restrict__ route_W,
                        const float* __restrict__ route_b,
                        const float* __restrict__ expert_w,
                        float* __restrict__ ws)
{
    int b = blockIdx.x, t = threadIdx.x;
    __shared__ float feat[512];
    __shared__ float rwv[5];
    __shared__ float red[256];
    int cl = cluster[b];
    feat[t]       = ws[OFF_POOLED + (size_t)b * 256 + t];
    feat[256 + t] = route_emb[(size_t)cl * 256 + t];
    __syncthreads();
    float f0 = feat[t], f1 = feat[256 + t];
    for (int e = 0; e < 5; e++) {
        float pv = f0 * route_W[e * 512 + t] + f1 * route_W[e * 512 + 256 + t];
        red[t] = pv;
        __syncthreads();
        if (t < 128) red[t] += red[t + 128];
        __syncthreads();
        if (t < 64) {
            float s = red[t] + red[t + 64];
            #pragma unroll
            for (int off = 32; off; off >>= 1) s += __shfl_down(s, off);
            if (t == 0) rwv[e] = sigmoidf_(s + route_b[e]);
        }
        __syncthreads();
    }
    float r0 = rwv[0], r1 = rwv[1], r2 = rwv[2], r3 = rwv[3], r4 = rwv[4];
    f16* khg = (f16*)(ws + OFF_KERN);
    for (int j = t; j < 4096; j += 256) {
        int oc = j >> 6, ic = j & 63;
        float kv = r0 * expert_w[j] + r1 * expert_w[4096 + j] +
                   r2 * expert_w[2 * 4096 + j] + r3 * expert_w[3 * 4096 + j] +
                   r4 * expert_w[4 * 4096 + j];
        khg[(size_t)b * 4096 + oc * 64 + (ic ^ ((oc & 7) << 3))] = (f16)kv;
    }
}

// ---------------------------------------------------------------------------
// F1 (MFMA): cc(1x1, A=kern M=oc, B=x N=pos) + gate + conv1 + prelu + pool
// -> h1h fp16 [b][576 pos][32 oc]
// LDS bytes: glds[10][50][72h] 0..72000 | wl 72000..108864 | kh 108864..117056
//            | cbl 117056..117312 | poolt[96][40h] 117312..124992
//            dump f32 [384][34] overlays glds (52224B)
// ---------------------------------------------------------------------------
__global__ void __launch_bounds__(512, 1)
k_f1(const float* __restrict__ x, const f16* __restrict__ kernH,
     const float* __restrict__ cond_b, const f16* __restrict__ w1H,
     const float* __restrict__ cb1, const float* __restrict__ a1,
     f16* __restrict__ h1h)
{
    extern __shared__ char smem[];
    f16*  glds  = (f16*)smem;
    f16*  wl    = (f16*)(smem + 72000);
    f16*  kh    = (f16*)(smem + 108864);
    float* cbl  = (float*)(smem + 117056);
    f16*  poolt = (f16*)(smem + 117312);
    float* dump = (float*)smem;

    const int t = threadIdx.x;
    const int tile = blockIdx.x;            // 0..5
    const int b = blockIdx.y;
    const int r0 = tile * 8;
    const int w = t >> 6, l = t & 63;
    const int l15 = l & 15, agrp = l >> 4;

    // ---- P0: stage weights/kern/cond_b, zero pad cols, stage x (float4) ----
    for (int e = t; e < 2304; e += 512) ((uint4*)wl)[e] = ((const uint4*)w1H)[e];
    ((uint4*)kh)[t] = ((const uint4*)(kernH + (size_t)b * 4096))[t];
    if (t < 64) cbl[t] = cond_b[t];
    for (int e = t; e < 640; e += 512) {          // zero cols 0 and 49
        int r = e / 64; int rem = e - r * 64;
        int col = (rem >= 32) ? 49 : 0;
        int icp = (rem & 31) * 2;
        *(f16x2*)&glds[(r * 50 + col) * 72 + icp] = (f16x2){(f16)0.f, (f16)0.f};
    }
    for (int e = t; e < 3840; e += 512) {
        int icp = e / 120;
        int rem = e - icp * 120;
        int srow = rem / 12;
        int cg = rem - srow * 12;
        int r_in = r0 - 1 + srow;
        float fa[4] = {0.f, 0.f, 0.f, 0.f}, fb[4] = {0.f, 0.f, 0.f, 0.f};
        if (r_in >= 0 && r_in < 48) {
            const float4* xp = (const float4*)x + ((size_t)(b * 64 + 2 * icp)) * 576 + r_in * 12 + cg;
            float4 va = xp[0], vb = xp[576];
            fa[0] = va.x; fa[1] = va.y; fa[2] = va.z; fa[3] = va.w;
            fb[0] = vb.x; fb[1] = vb.y; fb[2] = vb.z; fb[3] = vb.w;
        }
        int ic0 = 2 * icp;
        #pragma unroll
        for (int j2 = 0; j2 < 4; j2++) {
            int sc = 4 * cg + j2 + 1;
            int ix = ic0 ^ ((sc & 7) << 3);
            *(f16x2*)&glds[(srow * 50 + sc) * 72 + ix] = (f16x2){(f16)fa[j2], (f16)fb[j2]};
        }
    }
    __syncthreads();

    // ---- P1: cc 1x1 conv via MFMA (A=kern, B=x) + gate in place ----
    {
        f16x8 kfr[4][2];
        #pragma unroll
        for (int mt = 0; mt < 4; mt++) {
            int oc = mt * 16 + l15;
            #pragma unroll
            for (int ks = 0; ks < 2; ks++)
                kfr[mt][ks] = *(const f16x8*)&kh[oc * 64 + ((ks * 4 + agrp) ^ (oc & 7)) * 8];
        }
        const int nt0 = (w < 6) ? 4 * w : 24 + 3 * (w - 6);
        const int NT  = (w < 6) ? 4 : 3;
        f32x4 acc[4][4] = {};
        int srA[4], scA[4];
        #pragma unroll
        for (int j = 0; j < 4; j++) {
            int ntc = nt0 + ((j < NT) ? j : 0);      // clamp for waves 6,7
            int p = ntc * 16 + l15;                  // 0..479
            srA[j] = p / 48; scA[j] = p - 48 * srA[j] + 1;
        }
        #pragma unroll
        for (int j = 0; j < 4; j++) {
            int base = (srA[j] * 50 + scA[j]) * 72;
            int sw = scA[j] & 7;
            #pragma unroll
            for (int ks = 0; ks < 2; ks++) {
                f16x8 bfr = *(const f16x8*)&glds[base + ((ks * 4 + agrp) ^ sw) * 8];
                #pragma unroll
                for (int mt = 0; mt < 4; mt++)
                    acc[mt][j] = __builtin_amdgcn_mfma_f32_16x16x32_f16(kfr[mt][ks], bfr, acc[mt][j], 0, 0, 0);
            }
        }
        #pragma unroll
        for (int j = 0; j < 4; j++) {
            if (j < NT) {                            // wave-uniform
                int base = (srA[j] * 50 + scA[j]) * 72;
                int sw8 = (scA[j] & 7) << 3;
                #pragma unroll
                for (int mt = 0; mt < 4; mt++) {
                    #pragma unroll
                    for (int rr = 0; rr < 4; rr++) {
                        int oc = mt * 16 + 4 * agrp + rr;
                        int addr = base + (oc ^ sw8);
                        float xv = (float)glds[addr];
                        float gg = sigmoidf_(acc[mt][j][rr] + cbl[oc]);
                        glds[addr] = (f16)(gg * xv);
                    }
                }
            }
        }
    }
    __syncthreads();

    // ---- P2: conv1 3x3 via MFMA (A=x pos, B=w1 oc) ----
    f32x4 c2[3][2] = {};
    {
        const int q = w;   // out row 0..7
        #pragma unroll
        for (int kt = 0; kt < 18; kt++) {
            const int kk = kt >> 1, hh = kt & 1;
            const int dy = kk / 3, dx = kk - dy * 3;
            f16x8 bfr2[2];
            #pragma unroll
            for (int nt = 0; nt < 2; nt++) {
                int oc = nt * 16 + l15;
                int slot = (hh * 4 + agrp) ^ (oc & 7);
                bfr2[nt] = *(const f16x8*)&wl[(kk * 32 + oc) * 64 + slot * 8];
            }
            #pragma unroll
            for (int mtl = 0; mtl < 3; mtl++) {
                int c = mtl * 16 + l15;
                int sc = c + dx;
                int slot = (hh * 4 + agrp) ^ (sc & 7);
                f16x8 af = *(const f16x8*)&glds[((q + dy) * 50 + sc) * 72 + slot * 8];
                c2[mtl][0] = __builtin_amdgcn_mfma_f32_16x16x32_f16(af, bfr2[0], c2[mtl][0], 0, 0, 0);
                c2[mtl][1] = __builtin_amdgcn_mfma_f32_16x16x32_f16(af, bfr2[1], c2[mtl][1], 0, 0, 0);
            }
        }
    }
    __syncthreads();

    // ---- P3: dump raw conv acc to LDS [384 pos][34] f32 ----
    {
        const int q = w;
        #pragma unroll
        for (int mtl = 0; mtl < 3; mtl++)
            #pragma unroll
            for (int nt = 0; nt < 2; nt++)
                #pragma unroll
                for (int rr = 0; rr < 4; rr++) {
                    int pcl = mtl * 16 + 4 * agrp + rr;
                    dump[(q * 48 + pcl) * 34 + nt * 16 + l15] = c2[mtl][nt][rr];
                }
    }
    __syncthreads();

    // ---- P4: maxpool 2x2 + bias + prelu -> poolt fp16 [96 pos][40] ----
    {
        const float av = a1[0];
        #pragma unroll
        for (int k = 0; k < 6; k++) {
            int e = t + 512 * k;
            int oc = e & 31, pos2 = e >> 5;
            int pr = pos2 / 24, pc = pos2 - 24 * pr;
            int p0 = (2 * pr) * 48 + 2 * pc;
            float m = fmaxf(fmaxf(dump[p0 * 34 + oc], dump[(p0 + 1) * 34 + oc]),
                            fmaxf(dump[(p0 + 48) * 34 + oc], dump[(p0 + 49) * 34 + oc]));
            float v = m + cb1[oc];
            v = (v >= 0.0f) ? v : av * v;
            poolt[pos2 * 40 + oc] = (f16)v;
        }
    }
    __syncthreads();

    // ---- P5: coalesced write h1h [b][pos][32] ----
    if (t < 384) {
        int pos2 = t >> 2, slot = t & 3;
        uint4 val = *(const uint4*)&poolt[pos2 * 40 + slot * 8];
        ((uint4*)h1h)[((size_t)b * 576 + tile * 96 + pos2) * 4 + slot] = val;
    }
}

// ---------------------------------------------------------------------------
// F23 (MFMA): conv2+pool + conv3+pool + mean + emb + MLP, one block per sample
// LDS bytes: x2[26][26][40h] 0..54080 | w2l[576][40h] 54080..100160
//            | h2l[196][72h] 100160..128384 | ps 128384 | hb 130432
//            | t1 130944 | t2 131200  (total 131328)
//            dump2 [576][72h] overlays 0..82944 ; dump3 [144][136h] 0..39168
// ---------------------------------------------------------------------------
__global__ void __launch_bounds__(512, 1)
k_f23(const f16* __restrict__ h1h, const f16* __restrict__ w2h,
      const float* __restrict__ cb2, const float* __restrict__ a2,
      const f16* __restrict__ w3h, const float* __restrict__ cb3, const float* __restrict__ a3,
      const int* __restrict__ cluster, const float* __restrict__ emb2, const float* __restrict__ alpha,
      const float* __restrict__ mW1, const float* __restrict__ mb1, const float* __restrict__ a4,
      const float* __restrict__ mW2, const float* __restrict__ mb2, const float* __restrict__ a5,
      const float* __restrict__ mW3, const float* __restrict__ mb3,
      float* __restrict__ out)
{
    extern __shared__ char smem[];
    f16*  x2    = (f16*)smem;
    f16*  w2l   = (f16*)(smem + 54080);
    f16*  h2l   = (f16*)(smem + 100160);
    float* ps   = (float*)(smem + 128384);
    float* hb   = (float*)(smem + 130432);
    float* t1   = (float*)(smem + 130944);
    float* t2   = (float*)(smem + 131200);
    f16*  dump2 = (f16*)smem;
    f16*  dump3 = (f16*)smem;

    const int b = blockIdx.x, t = threadIdx.x;
    const int w = t >> 6, l = t & 63;
    const int l15 = l & 15, agrp = l >> 4;

    // ---- P0: zero borders + stage x2 + stage w2l ----
    for (int e = t; e < 400; e += 512) {          // x2 border: 100 pos x 4 uint4
        int bp = e >> 2, slot = e & 3;
        int r, c;
        if (bp < 26)      { r = 0;  c = bp; }
        else if (bp < 52) { r = 25; c = bp - 26; }
        else if (bp < 76) { r = bp - 52 + 1; c = 0; }
        else              { r = bp - 76 + 1; c = 25; }
        uint4 z = {};
        *(uint4*)&x2[(r * 26 + c) * 40 + slot * 8] = z;
    }
    for (int e = t; e < 416; e += 512) {          // h2l border: 52 pos x 8 uint4
        int bp = e >> 3, slot = e & 7;
        int r, c;
        if (bp < 14)      { r = 0;  c = bp; }
        else if (bp < 28) { r = 13; c = bp - 14; }
        else if (bp < 40) { r = bp - 28 + 1; c = 0; }
        else              { r = bp - 40 + 1; c = 13; }
        uint4 z = {};
        *(uint4*)&h2l[(r * 14 + c) * 72 + slot * 8] = z;
    }
    {
        const uint4* src = (const uint4*)(h1h + (size_t)b * 18432);
        for (int e = t; e < 2304; e += 512) {
            int pos = e >> 2, slot = e & 3;
            int r = pos / 24, c = pos - 24 * r;
            *(uint4*)&x2[((r + 1) * 26 + (c + 1)) * 40 + slot * 8] = src[e];
        }
    }
    {
        const uint4* src = (const uint4*)w2h;
        for (int e = t; e < 2304; e += 512) {
            int row = e >> 2, slot = e & 3;
            *(uint4*)&w2l[row * 40 + slot * 8] = src[e];
        }
    }
    __syncthreads();

    // ---- P1: conv2 MFMA (A=w2 M=oc, B=x2 N=pos). wave: octile=w&3, poshalf=w>>2
    const int m = w & 3, half = w >> 2;
    f32x4 acc[18];
    {
        f16x8 afr[9];
        #pragma unroll
        for (int kk = 0; kk < 9; kk++)
            afr[kk] = *(const f16x8*)&w2l[(kk * 64 + m * 16 + l15) * 40 + agrp * 8];
        #pragma unroll
        for (int nt = 0; nt < 18; nt++) acc[nt] = (f32x4){0.f, 0.f, 0.f, 0.f};
        constexpr int K2[9] = {0, 40, 80, 26 * 40, 27 * 40, 28 * 40, 52 * 40, 53 * 40, 54 * 40};
        #pragma unroll
        for (int nt = 0; nt < 18; nt++) {
            int p = (half * 18 + nt) * 16 + l15;
            int r = p / 24, c = p - 24 * r;
            int base = (r * 26 + c) * 40 + agrp * 8;
            #pragma unroll
            for (int kk = 0; kk < 9; kk++) {
                f16x8 bfr = *(const f16x8*)&x2[base + K2[kk]];
                acc[nt] = __builtin_amdgcn_mfma_f32_16x16x32_f16(afr[kk], bfr, acc[nt], 0, 0, 0);
            }
        }
    }
    __syncthreads();

    // ---- P2: dump2 [576][72] fp16 ----
    #pragma unroll
    for (int nt = 0; nt < 18; nt++) {
        int p = (half * 18 + nt) * 16 + l15;
        #pragma unroll
        for (int rr = 0; rr < 4; rr++) {
            int oc = m * 16 + 4 * agrp + rr;
            dump2[p * 72 + oc] = (f16)acc[nt][rr];
        }
    }
    __syncthreads();

    // ---- P3: pool conv2 + bias + prelu -> h2l [14][14][72] padded ----
    {
        const float a2v = a2[0];
        for (int e = t; e < 9216; e += 512) {
            int oc = e & 63, pos2 = e >> 6;
            int pr = pos2 / 12, pc = pos2 - 12 * pr;
            int p0 = (2 * pr) * 24 + 2 * pc;
            float mm = fmaxf(fmaxf((float)dump2[p0 * 72 + oc], (float)dump2[(p0 + 1) * 72 + oc]),
                             fmaxf((float)dump2[(p0 + 24) * 72 + oc], (float)dump2[(p0 + 25) * 72 + oc]));
            float v = mm + cb2[oc];
            v = (v >= 0.0f) ? v : a2v * v;
            h2l[((pr + 1) * 14 + (pc + 1)) * 72 + oc] = (f16)v;
        }
    }
    __syncthreads();

    // ---- P4: conv3 MFMA (A=w3 from GLOBAL, M-tile = w; B=h2l N=pos) ----
    f32x4 acc9[9];
    {
        int pb[9];
        #pragma unroll
        for (int nt = 0; nt < 9; nt++) {
            int p = nt * 16 + l15;
            int r = p / 12, c = p - 12 * r;
            pb[nt] = (r * 14 + c) * 72 + agrp * 8;
            acc9[nt] = (f32x4){0.f, 0.f, 0.f, 0.f};
        }
        constexpr int K3[9] = {0, 72, 144, 14 * 72, 15 * 72, 16 * 72, 28 * 72, 29 * 72, 30 * 72};
        #pragma unroll
        for (int kk = 0; kk < 9; kk++) {
            #pragma unroll
            for (int ks = 0; ks < 2; ks++) {
                f16x8 afr = *(const f16x8*)&w3h[(size_t)(kk * 128 + w * 16 + l15) * 64 + ks * 32 + agrp * 8];
                #pragma unroll
                for (int nt = 0; nt < 9; nt++) {
                    f16x8 bfr = *(const f16x8*)&h2l[pb[nt] + ks * 32 + K3[kk]];
                    acc9[nt] = __builtin_amdgcn_mfma_f32_16x16x32_f16(afr, bfr, acc9[nt], 0, 0, 0);
                }
            }
        }
    }
    // ---- P5: dump3 [144][136] fp16 (region dead since P3; disjoint from h2l) ----
    #pragma unroll
    for (int nt = 0; nt < 9; nt++) {
        int p = nt * 16 + l15;
        #pragma unroll
        for (int rr = 0; rr < 4; rr++) {
            int oc = w * 16 + 4 * agrp + rr;
            dump3[p * 136 + oc] = (f16)acc9[nt][rr];
        }
    }
    __syncthreads();

    // ---- P6: pool conv3 + bias + prelu + 9-element partial mean ----
    {
        int oc = t >> 2, q = t & 3;
        int qr = q >> 1, qc = q & 1;
        const float a3v = a3[0];
        float cbv = cb3[oc];
        float s = 0.f;
        #pragma unroll
        for (int i = 0; i < 3; i++)
            #pragma unroll
            for (int j = 0; j < 3; j++) {
                int pr = 3 * qr + i, pc = 3 * qc + j;
                int p0 = (2 * pr) * 12 + 2 * pc;
                float mm = fmaxf(fmaxf((float)dump3[p0 * 136 + oc], (float)dump3[(p0 + 1) * 136 + oc]),
                                 fmaxf((float)dump3[(p0 + 12) * 136 + oc], (float)dump3[(p0 + 13) * 136 + oc]));
                float v = mm + cbv;
                v = (v >= 0.0f) ? v : a3v * v;
                s += v;
            }
        ps[t] = s;
    }
    __syncthreads();
    if (t < 128) {
        int cl = cluster[b];
        hb[t] = (ps[4 * t] + ps[4 * t + 1] + ps[4 * t + 2] + ps[4 * t + 3]) * (1.0f / 36.0f)
              + emb2[(size_t)cl * 128 + t] * alpha[0];
    }
    __syncthreads();
    if (t < 64) {
        const float4* wr = (const float4*)(mW1 + t * 128);
        float s = mb1[t];
        #pragma unroll 8
        for (int j = 0; j < 32; j++) {
            float4 wv4 = wr[j];
            s += wv4.x * hb[4 * j] + wv4.y * hb[4 * j + 1] + wv4.z * hb[4 * j + 2] + wv4.w * hb[4 * j + 3];
        }
        float a4v = a4[0];
        t1[t] = (s >= 0.0f) ? s : a4v * s;
    }
    __syncthreads();
    if (t < 32) {
        const float4* wr = (const float4*)(mW2 + t * 64);
        float s = mb2[t];
        #pragma unroll
        for (int j = 0; j < 16; j++) {
            float4 wv4 = wr[j];
            s += wv4.x * t1[4 * j] + wv4.y * t1[4 * j + 1] + wv4.z * t1[4 * j + 2] + wv4.w * t1[4 * j + 3];
        }
        float a5v = a5[0];
        t2[t] = (s >= 0.0f) ? s : a5v * s;
    }
    __syncthreads();
    if (t < 65) {
        const float4* wr = (const float4*)(mW3 + t * 32);
        float s = mb3[t];
        #pragma unroll
        for (int j = 0; j < 8; j++) {
            float4 wv4 = wr[j];
            s += wv4.x * t2[4 * j] + wv4.y * t2[4 * j + 1] + wv4.z * t2[4 * j + 2] + wv4.w * t2[4 * j + 3];
        }
        out[(size_t)b * 65 + t] = s;
    }
}

// ---------------------------------------------------------------------------
extern "C" void kernel_launch(void* const* d_in, const int* in_sizes, int n_in,
                              void* d_out, int out_size, void* d_ws, size_t ws_size,
                              hipStream_t stream)
{
    const float* x         = (const float*)d_in[0];
    const int*   cluster   = (const int*)  d_in[1];
    const float* expert_w  = (const float*)d_in[2];
    const float* cond_b    = (const float*)d_in[3];
    const float* route_emb = (const float*)d_in[4];
    const float* route_W   = (const float*)d_in[5];
    const float* route_b   = (const float*)d_in[6];
    const float* v1  = (const float*)d_in[7];
    const float* g1  = (const float*)d_in[8];
    const float* cb1 = (const float*)d_in[9];
    const float* a1  = (const float*)d_in[10];
    const float* v2  = (const float*)d_in[11];
    const float* g2  = (const float*)d_in[12];
    const float* cb2 = (const float*)d_in[13];
    const float* a2  = (const float*)d_in[14];
    const float* v3  = (const float*)d_in[15];
    const float* g3  = (const float*)d_in[16];
    const float* cb3 = (const float*)d_in[17];
    const float* a3  = (const float*)d_in[18];
    const float* emb2  = (const float*)d_in[19];
    const float* alpha = (const float*)d_in[20];
    const float* mW1 = (const float*)d_in[21];
    const float* mb1 = (const float*)d_in[22];
    const float* a4  = (const float*)d_in[23];
    const float* mW2 = (const float*)d_in[24];
    const float* mb2 = (const float*)d_in[25];
    const float* a5  = (const float*)d_in[26];
    const float* mW3 = (const float*)d_in[27];
    const float* mb3 = (const float*)d_in[28];
    float* ws  = (float*)d_ws;
    float* out = (float*)d_out;

    hipFuncSetAttribute((const void*)k_f1,  hipFuncAttributeMaxDynamicSharedMemorySize, 124992);
    hipFuncSetAttribute((const void*)k_f23, hipFuncAttributeMaxDynamicSharedMemorySize, 131328);

    k_wnorm<<<224, 256, 0, stream>>>(v1, g1, v2, g2, v3, g3, ws);
    k_pool<<<16384, 64, 0, stream>>>(x, ws);
    k_route<<<256, 256, 0, stream>>>(cluster, route_emb, route_W, route_b, expert_w, ws);
    k_f1<<<dim3(6, 256), 512, 124992, stream>>>(x, (const f16*)(ws + OFF_KERN), cond_b,
                                                (const f16*)(ws + OFF_W1), cb1, a1,
                                                (f16*)(ws + OFF_H1));
    k_f23<<<256, 512, 131328, stream>>>((const f16*)(ws + OFF_H1), (const f16*)(ws + OFF_W2),
                                        cb2, a2, (const f16*)(ws + OFF_W3), cb3, a3,
                                        cluster, emb2, alpha,
                                        mW1, mb1, a4, mW2, mb2, a5, mW3, mb3, out);
}

// Round 5
// 131.372 us; speedup vs baseline: 7.1412x; 1.3912x over previous
//
#include <hip/hip_runtime.h>

// Problem constants: B=256, C=64, H=W=48, E=5, DIM=65

typedef _Float16 f16;
typedef f16 f16x8 __attribute__((ext_vector_type(8)));
typedef f16 f16x4 __attribute__((ext_vector_type(4)));
typedef float f32x4 __attribute__((ext_vector_type(4)));

constexpr size_t OFF_POOLED = 0;                       // 256*256 f32
constexpr size_t OFF_KERN   = 65536;                   // 256*4096 f16 (swizzled [b][oc][ic^((oc&7)<<3)])
constexpr size_t OFF_W1     = 65536 + 1048576;         // 9*32*64 f16 swizzled [kk][oc][ic^((oc&7)<<3)]
constexpr size_t OFF_W2     = OFF_W1 + 32*64*12;       // 9*64*32 f16 linear [kk][oc][ic]
constexpr size_t OFF_W3     = OFF_W2 + 64*32*12;       // 9*128*64 f16 linear [kk][oc][ic]
constexpr size_t OFF_H1     = OFF_W3 + 128*64*12;      // 256*576*32 f16 channel-last [b][pos][ic]

__device__ __forceinline__ float sigmoidf_(float z) {
    return 1.0f / (1.0f + __expf(-z));
}

// build f16x8 from 8 floats (static indices) and store swizzled
__device__ __forceinline__ void store_slot8(f16* glds, int row, int sc, int icg, const float* c) {
    f16x8 hv = { (f16)c[0], (f16)c[1], (f16)c[2], (f16)c[3],
                 (f16)c[4], (f16)c[5], (f16)c[6], (f16)c[7] };
    *(f16x8*)&glds[(row * 50 + sc) * 64 + ((icg ^ (sc & 7)) << 3)] = hv;
}

// ---------------------------------------------------------------------------
// K0: weight-norm.
//  w1 -> fp16 swizzled [kk][32 oc][64 ic ^ ((oc&7)<<3)]
//  w2 -> fp16 linear  [kk][64 oc][32 ic]
//  w3 -> fp16 linear  [kk][128 oc][64 ic]
// ---------------------------------------------------------------------------
__global__ void k_wnorm(const float* __restrict__ v1, const float* __restrict__ g1,
                        const float* __restrict__ v2, const float* __restrict__ g2,
                        const float* __restrict__ v3, const float* __restrict__ g3,
                        float* __restrict__ ws)
{
    int bo = blockIdx.x;
    const float* v; const float* g; int IC, oc; int which;
    if (bo < 32)       { v = v1; g = g1; oc = bo;      IC = 64; which = 1; }
    else if (bo < 96)  { v = v2; g = g2; oc = bo - 32; IC = 32; which = 2; }
    else               { v = v3; g = g3; oc = bo - 96; IC = 64; which = 3; }
    int n = IC * 9;
    const float* vo = v + (size_t)oc * n;
    float s = 0.0f;
    for (int i = threadIdx.x; i < n; i += 256) { float xv = vo[i]; s += xv * xv; }
    __shared__ float swarp[4];
    __shared__ float sscale;
    int lane = threadIdx.x & 63, wid = threadIdx.x >> 6;
    #pragma unroll
    for (int off = 32; off; off >>= 1) s += __shfl_down(s, off);
    if (lane == 0) swarp[wid] = s;
    __syncthreads();
    if (threadIdx.x == 0) {
        float tsum = swarp[0] + swarp[1] + swarp[2] + swarp[3];
        sscale = g[oc] / sqrtf(tsum);
    }
    __syncthreads();
    float sc = sscale;
    if (which == 1) {
        f16* o1 = (f16*)(ws + OFF_W1);
        for (int i = threadIdx.x; i < n; i += 256) {
            int ic = i / 9, kk = i - ic * 9;
            o1[kk * 2048 + oc * 64 + (ic ^ ((oc & 7) << 3))] = (f16)(vo[i] * sc);
        }
    } else if (which == 2) {
        f16* o2 = (f16*)(ws + OFF_W2);
        for (int i = threadIdx.x; i < n; i += 256) {
            int ic = i / 9, kk = i - ic * 9;
            o2[(kk * 64 + oc) * 32 + ic] = (f16)(vo[i] * sc);
        }
    } else {
        f16* o3 = (f16*)(ws + OFF_W3);
        for (int i = threadIdx.x; i < n; i += 256) {
            int ic = i / 9, kk = i - ic * 9;
            o3[(kk * 128 + oc) * 64 + ic] = (f16)(vo[i] * sc);
        }
    }
}

// ---------------------------------------------------------------------------
// K1: adaptive avg-pool 2x2, one wave per (b,c) slab, float4 loads
// ---------------------------------------------------------------------------
__global__ void __launch_bounds__(64)
k_pool(const float* __restrict__ x, float* __restrict__ ws)
{
    int bc = blockIdx.x;
    int lane = threadIdx.x;
    const float4* p = (const float4*)(x + (size_t)bc * 2304);
    float a0 = 0.f, a1 = 0.f, a2 = 0.f, a3 = 0.f;
    #pragma unroll
    for (int j = 0; j < 9; j++) {
        int i = lane + 64 * j;            // < 576
        int row = i / 12, cg = i - 12 * row;
        float4 v = p[i];
        float s = v.x + v.y + v.z + v.w;
        bool hq = (row >= 24), wq = (cg >= 6);
        a0 += (!hq && !wq) ? s : 0.f;
        a1 += (!hq &&  wq) ? s : 0.f;
        a2 += ( hq && !wq) ? s : 0.f;
        a3 += ( hq &&  wq) ? s : 0.f;
    }
    #pragma unroll
    for (int off = 32; off; off >>= 1) {
        a0 += __shfl_down(a0, off);
        a1 += __shfl_down(a1, off);
        a2 += __shfl_down(a2, off);
        a3 += __shfl_down(a3, off);
    }
    if (lane == 0) {
        int b = bc >> 6, c = bc & 63;
        float* d = ws + OFF_POOLED + (size_t)b * 256 + c * 4;
        d[0] = a0 * (1.0f / 576.0f);
        d[1] = a1 * (1.0f / 576.0f);
        d[2] = a2 * (1.0f / 576.0f);
        d[3] = a3 * (1.0f / 576.0f);
    }
}

// ---------------------------------------------------------------------------
// K2: routing + expert-mixed 1x1 kern -> fp16 swizzled [b][oc][ic^((oc&7)<<3)]
// ---------------------------------------------------------------------------
__global__ void k_route(const int* __restrict__ cluster,
                        const float* __restrict__ route_emb,
                        const float* __restrict__ route_W,
                        const float* __restrict__ route_b,
                        const float* __restrict__ expert_w,
                        float* __restrict__ ws)
{
    int b = blockIdx.x, t = threadIdx.x;
    __shared__ float feat[512];
    __shared__ float rwv[5];
    __shared__ float red[256];
    int cl = cluster[b];
    feat[t]       = ws[OFF_POOLED + (size_t)b * 256 + t];
    feat[256 + t] = route_emb[(size_t)cl * 256 + t];
    __syncthreads();
    float f0 = feat[t], f1 = feat[256 + t];
    for (int e = 0; e < 5; e++) {
        float pv = f0 * route_W[e * 512 + t] + f1 * route_W[e * 512 + 256 + t];
        red[t] = pv;
        __syncthreads();
        if (t < 128) red[t] += red[t + 128];
        __syncthreads();
        if (t < 64) {
            float s = red[t] + red[t + 64];
            #pragma unroll
            for (int off = 32; off; off >>= 1) s += __shfl_down(s, off);
            if (t == 0) rwv[e] = sigmoidf_(s + route_b[e]);
        }
        __syncthreads();
    }
    float r0 = rwv[0], r1 = rwv[1], r2 = rwv[2], r3 = rwv[3], r4 = rwv[4];
    f16* khg = (f16*)(ws + OFF_KERN);
    for (int j = t; j < 4096; j += 256) {
        int oc = j >> 6, ic = j & 63;
        float kv = r0 * expert_w[j] + r1 * expert_w[4096 + j] +
                   r2 * expert_w[2 * 4096 + j] + r3 * expert_w[3 * 4096 + j] +
                   r4 * expert_w[4 * 4096 + j];
        khg[(size_t)b * 4096 + oc * 64 + (ic ^ ((oc & 7) << 3))] = (f16)kv;
    }
}

// ---------------------------------------------------------------------------
// F1 (MFMA): cc(1x1, A=kern M=oc, B=x N=pos) + gate + conv1 + prelu + pool
// -> h1h fp16 [b][576 pos][32 oc]
// LDS: glds fp16 [10][50][64] (XOR slot swizzle) 0..64000 | kh 64000..72192
//      | cbl 72192..72448.  Total 72448 B -> 2 blocks/CU.
// dump f32 [384][34] overlays glds 0..52224; poolt fp16 [96][40] at 52224..59904
// w1 B-fragments are read directly from global (L2-hot, shared by all blocks).
// ---------------------------------------------------------------------------
__global__ void __launch_bounds__(512, 4)
k_f1(const float* __restrict__ x, const f16* __restrict__ kernH,
     const float* __restrict__ cond_b, const f16* __restrict__ w1H,
     const float* __restrict__ cb1, const float* __restrict__ a1,
     f16* __restrict__ h1h)
{
    extern __shared__ char smem[];
    f16*  glds  = (f16*)smem;                  // 64000 B
    f16*  kh    = (f16*)(smem + 64000);        // 8192 B
    float* cbl  = (float*)(smem + 72192);      // 256 B
    float* dump = (float*)smem;                // overlay
    f16*  poolt = (f16*)(smem + 52224);        // overlay

    const int t = threadIdx.x;
    const int tile = blockIdx.x;            // 0..5
    const int b = blockIdx.y;
    const int r0 = tile * 8;
    const int w = t >> 6, l = t & 63;
    const int l15 = l & 15, agrp = l >> 4;

    // ---- P0: stage kern + cond_b, zero border cols, stage x (8x4 reg transpose) ----
    ((uint4*)kh)[t] = ((const uint4*)(kernH + (size_t)b * 4096))[t];
    if (t < 64) cbl[t] = cond_b[t];
    if (t < 160) {                             // cols 0 and 49, all rows/slots
        int row = t >> 4, rem = t & 15;
        int col = (rem >= 8) ? 49 : 0;
        int slot = rem & 7;
        uint4 z = {};
        *(uint4*)&glds[(row * 50 + col) * 64 + slot * 8] = z;
    }
    for (int e = t; e < 960; e += 512) {
        int row = e / 96;                      // 0..9
        int rem = e - row * 96;
        int colg = rem >> 3;                   // 0..11
        int icg = rem & 7;                     // 0..7
        int r_in = r0 - 1 + row;
        float4 va[8];
        if (r_in >= 0 && r_in < 48) {
            const float4* xp = (const float4*)x + ((size_t)(b * 64 + icg * 8)) * 576 + r_in * 12 + colg;
            #pragma unroll
            for (int i = 0; i < 8; i++) va[i] = xp[i * 576];
        } else {
            #pragma unroll
            for (int i = 0; i < 8; i++) va[i] = (float4){0.f, 0.f, 0.f, 0.f};
        }
        float c0[8], c1[8], c2c[8], c3[8];
        #pragma unroll
        for (int i = 0; i < 8; i++) { c0[i] = va[i].x; c1[i] = va[i].y; c2c[i] = va[i].z; c3[i] = va[i].w; }
        int scb = colg * 4 + 1;
        store_slot8(glds, row, scb + 0, icg, c0);
        store_slot8(glds, row, scb + 1, icg, c1);
        store_slot8(glds, row, scb + 2, icg, c2c);
        store_slot8(glds, row, scb + 3, icg, c3);
    }
    __syncthreads();

    // ---- P1: cc 1x1 conv via MFMA (A=kern, B=x) + gate in place ----
    {
        const int nt0 = (w < 6) ? 4 * w : 24 + 3 * (w - 6);
        const int NT  = (w < 6) ? 4 : 3;
        f32x4 acc[4][4] = {};
        int srA[4], scA[4];
        #pragma unroll
        for (int j = 0; j < 4; j++) {
            int ntc = nt0 + ((j < NT) ? j : 0);
            int p = ntc * 16 + l15;
            srA[j] = p / 48; scA[j] = p - 48 * srA[j] + 1;
        }
        #pragma unroll
        for (int ks = 0; ks < 2; ks++) {
            f16x8 kfr[4];
            #pragma unroll
            for (int mt = 0; mt < 4; mt++) {
                int oc = mt * 16 + l15;
                kfr[mt] = *(const f16x8*)&kh[oc * 64 + (((ks * 4 + agrp) ^ (oc & 7)) << 3)];
            }
            #pragma unroll
            for (int j = 0; j < 4; j++) {
                f16x8 bfr = *(const f16x8*)&glds[(srA[j] * 50 + scA[j]) * 64 +
                                                 (((ks * 4 + agrp) ^ (scA[j] & 7)) << 3)];
                #pragma unroll
                for (int mt = 0; mt < 4; mt++)
                    acc[mt][j] = __builtin_amdgcn_mfma_f32_16x16x32_f16(kfr[mt], bfr, acc[mt][j], 0, 0, 0);
            }
        }
        #pragma unroll
        for (int j = 0; j < 4; j++) {
            if (j < NT) {                            // wave-uniform
                int base = (srA[j] * 50 + scA[j]) * 64;
                int sw8 = (scA[j] & 7) << 3;
                #pragma unroll
                for (int mt = 0; mt < 4; mt++) {
                    #pragma unroll
                    for (int rr = 0; rr < 4; rr++) {
                        int oc = mt * 16 + 4 * agrp + rr;
                        int addr = base + (oc ^ sw8);
                        float xv = (float)glds[addr];
                        float gg = sigmoidf_(acc[mt][j][rr] + cbl[oc]);
                        glds[addr] = (f16)(gg * xv);
                    }
                }
            }
        }
    }
    __syncthreads();

    // ---- P2: conv1 3x3 via MFMA (A=x pos, B=w1 oc from GLOBAL) ----
    f32x4 c2[3][2] = {};
    {
        const int q = w;   // out row 0..7
        #pragma unroll
        for (int kt = 0; kt < 18; kt++) {
            const int kk = kt >> 1, hh = kt & 1;
            const int dy = kk / 3, dx = kk - dy * 3;
            f16x8 bfr2[2];
            #pragma unroll
            for (int nt = 0; nt < 2; nt++) {
                int oc = nt * 16 + l15;
                int slot = (hh * 4 + agrp) ^ (oc & 7);
                bfr2[nt] = *(const f16x8*)&w1H[(kk * 32 + oc) * 64 + slot * 8];
            }
            #pragma unroll
            for (int mtl = 0; mtl < 3; mtl++) {
                int sc = mtl * 16 + l15 + dx;
                int slot = (hh * 4 + agrp) ^ (sc & 7);
                f16x8 af = *(const f16x8*)&glds[((q + dy) * 50 + sc) * 64 + slot * 8];
                c2[mtl][0] = __builtin_amdgcn_mfma_f32_16x16x32_f16(af, bfr2[0], c2[mtl][0], 0, 0, 0);
                c2[mtl][1] = __builtin_amdgcn_mfma_f32_16x16x32_f16(af, bfr2[1], c2[mtl][1], 0, 0, 0);
            }
        }
    }
    __syncthreads();   // glds reads done; dump overlays

    // ---- P3: dump raw conv acc to LDS [384 pos][34] f32 ----
    {
        const int q = w;
        #pragma unroll
        for (int mtl = 0; mtl < 3; mtl++)
            #pragma unroll
            for (int nt = 0; nt < 2; nt++)
                #pragma unroll
                for (int rr = 0; rr < 4; rr++) {
                    int pcl = mtl * 16 + 4 * agrp + rr;
                    dump[(q * 48 + pcl) * 34 + nt * 16 + l15] = c2[mtl][nt][rr];
                }
    }
    __syncthreads();

    // ---- P4: maxpool 2x2 + bias + prelu -> poolt fp16 [96 pos][40] ----
    {
        const float av = a1[0];
        #pragma unroll
        for (int k = 0; k < 6; k++) {
            int e = t + 512 * k;
            int oc = e & 31, pos2 = e >> 5;
            int pr = pos2 / 24, pc = pos2 - 24 * pr;
            int p0 = (2 * pr) * 48 + 2 * pc;
            float m = fmaxf(fmaxf(dump[p0 * 34 + oc], dump[(p0 + 1) * 34 + oc]),
                            fmaxf(dump[(p0 + 48) * 34 + oc], dump[(p0 + 49) * 34 + oc]));
            float v = m + cb1[oc];
            v = (v >= 0.0f) ? v : av * v;
            poolt[pos2 * 40 + oc] = (f16)v;
        }
    }
    __syncthreads();

    // ---- P5: coalesced write h1h [b][pos][32] ----
    if (t < 384) {
        int pos2 = t >> 2, slot = t & 3;
        uint4 val = *(const uint4*)&poolt[pos2 * 40 + slot * 8];
        ((uint4*)h1h)[((size_t)b * 576 + tile * 96 + pos2) * 4 + slot] = val;
    }
}

// ---------------------------------------------------------------------------
// F23 (MFMA): conv2+pool + conv3+pool + mean + emb + MLP, one block per sample
// 512 threads / 8 waves (round-3-proven decomposition).
// Weights w2/w3 read from global (L2-hot, no LDS staging).
// LDS: x2[26][26][40h] 0..54080 | h2l[14][14][72h] 82944..111168
//      | ps 111168..113216 | hb 113216..113728 | t1 ..113984 | t2 ..114112
//      dump2 fp16 [576][72] overlays 0..82944 ; dump3 fp16 [144][136] 0..39168
// ---------------------------------------------------------------------------
__global__ void __launch_bounds__(512, 1)
k_f23(const f16* __restrict__ h1h, const f16* __restrict__ w2h,
      const float* __restrict__ cb2, const float* __restrict__ a2,
      const f16* __restrict__ w3h, const float* __restrict__ cb3, const float* __restrict__ a3,
      const int* __restrict__ cluster, const float* __restrict__ emb2, const float* __restrict__ alpha,
      const float* __restrict__ mW1, const float* __restrict__ mb1, const float* __restrict__ a4,
      const float* __restrict__ mW2, const float* __restrict__ mb2, const float* __restrict__ a5,
      const float* __restrict__ mW3, const float* __restrict__ mb3,
      float* __restrict__ out)
{
    extern __shared__ char smem[];
    f16*  x2    = (f16*)smem;
    f16*  h2l   = (f16*)(smem + 82944);
    float* ps   = (float*)(smem + 111168);
    float* hb   = (float*)(smem + 113216);
    float* t1   = (float*)(smem + 113728);
    float* t2   = (float*)(smem + 113984);
    f16*  dump2 = (f16*)smem;
    f16*  dump3 = (f16*)smem;

    const int b = blockIdx.x, t = threadIdx.x;
    const int w = t >> 6, l = t & 63;
    const int l15 = l & 15, agrp = l >> 4;

    // ---- P0: zero borders + stage x2 ----
    for (int e = t; e < 400; e += 512) {          // x2 border: 100 pos x 4 uint4
        int bp = e >> 2, slot = e & 3;
        int r, c;
        if (bp < 26)      { r = 0;  c = bp; }
        else if (bp < 52) { r = 25; c = bp - 26; }
        else if (bp < 76) { r = bp - 52 + 1; c = 0; }
        else              { r = bp - 76 + 1; c = 25; }
        uint4 z = {};
        *(uint4*)&x2[(r * 26 + c) * 40 + slot * 8] = z;
    }
    for (int e = t; e < 416; e += 512) {          // h2l border: 52 pos x 8 uint4
        int bp = e >> 3, slot = e & 7;
        int r, c;
        if (bp < 14)      { r = 0;  c = bp; }
        else if (bp < 28) { r = 13; c = bp - 14; }
        else if (bp < 40) { r = bp - 28 + 1; c = 0; }
        else              { r = bp - 40 + 1; c = 13; }
        uint4 z = {};
        *(uint4*)&h2l[(r * 14 + c) * 72 + slot * 8] = z;
    }
    {
        const uint4* src = (const uint4*)(h1h + (size_t)b * 18432);
        for (int e = t; e < 2304; e += 512) {
            int pos = e >> 2, slot = e & 3;
            int r = pos / 24, c = pos - 24 * r;
            *(uint4*)&x2[((r + 1) * 26 + (c + 1)) * 40 + slot * 8] = src[e];
        }
    }
    __syncthreads();

    // ---- P1: conv2 MFMA (A=w2 global M=oc, B=x2 N=pos) ----
    // wave: m = w&3 (oc tile), half = w>>2 (0..1); 18 N-tiles each -> 36 total
    const int m = w & 3, half = w >> 2;
    f32x4 acc[18];
    {
        f16x8 afr[9];
        #pragma unroll
        for (int kk = 0; kk < 9; kk++)
            afr[kk] = *(const f16x8*)&w2h[(kk * 64 + m * 16 + l15) * 32 + agrp * 8];
        #pragma unroll
        for (int nt = 0; nt < 18; nt++) acc[nt] = (f32x4){0.f, 0.f, 0.f, 0.f};
        constexpr int K2[9] = {0, 40, 80, 26 * 40, 27 * 40, 28 * 40, 52 * 40, 53 * 40, 54 * 40};
        #pragma unroll
        for (int nt = 0; nt < 18; nt++) {
            int p = (half * 18 + nt) * 16 + l15;
            int r = p / 24, c = p - 24 * r;
            int base = (r * 26 + c) * 40 + agrp * 8;
            #pragma unroll
            for (int kk = 0; kk < 9; kk++) {
                f16x8 bfr = *(const f16x8*)&x2[base + K2[kk]];
                acc[nt] = __builtin_amdgcn_mfma_f32_16x16x32_f16(afr[kk], bfr, acc[nt], 0, 0, 0);
            }
        }
    }
    __syncthreads();

    // ---- P2: dump2 [576][72] fp16 (f16x4: lane holds 4 consecutive oc) ----
    #pragma unroll
    for (int nt = 0; nt < 18; nt++) {
        int p = (half * 18 + nt) * 16 + l15;
        f16x4 hv = { (f16)acc[nt][0], (f16)acc[nt][1], (f16)acc[nt][2], (f16)acc[nt][3] };
        *(f16x4*)&dump2[p * 72 + m * 16 + 4 * agrp] = hv;
    }
    __syncthreads();

    // ---- P3: pool conv2 + bias + prelu -> h2l [14][14][72] padded ----
    {
        const float a2v = a2[0];
        for (int e = t; e < 9216; e += 512) {
            int oc = e & 63, pos2 = e >> 6;
            int pr = pos2 / 12, pc = pos2 - 12 * pr;
            int p0 = (2 * pr) * 24 + 2 * pc;
            float mm = fmaxf(fmaxf((float)dump2[p0 * 72 + oc], (float)dump2[(p0 + 1) * 72 + oc]),
                             fmaxf((float)dump2[(p0 + 24) * 72 + oc], (float)dump2[(p0 + 25) * 72 + oc]));
            float v = mm + cb2[oc];
            v = (v >= 0.0f) ? v : a2v * v;
            h2l[((pr + 1) * 14 + (pc + 1)) * 72 + oc] = (f16)v;
        }
    }
    __syncthreads();

    // ---- P4: conv3 MFMA (A=w3 global M=oc tile=w, B=h2l N=pos, 9 N-tiles) ----
    f32x4 acc9[9];
    {
        int pb[9];
        #pragma unroll
        for (int nt = 0; nt < 9; nt++) {
            int p = nt * 16 + l15;
            int r = p / 12, c = p - 12 * r;
            pb[nt] = (r * 14 + c) * 72 + agrp * 8;
            acc9[nt] = (f32x4){0.f, 0.f, 0.f, 0.f};
        }
        constexpr int K3[9] = {0, 72, 144, 14 * 72, 15 * 72, 16 * 72, 28 * 72, 29 * 72, 30 * 72};
        #pragma unroll
        for (int kk = 0; kk < 9; kk++) {
            #pragma unroll
            for (int ks = 0; ks < 2; ks++) {
                f16x8 afr = *(const f16x8*)&w3h[(size_t)(kk * 128 + w * 16 + l15) * 64 + ks * 32 + agrp * 8];
                #pragma unroll
                for (int nt = 0; nt < 9; nt++) {
                    f16x8 bfr = *(const f16x8*)&h2l[pb[nt] + ks * 32 + K3[kk]];
                    acc9[nt] = __builtin_amdgcn_mfma_f32_16x16x32_f16(afr, bfr, acc9[nt], 0, 0, 0);
                }
            }
        }
    }
    // ---- P5: dump3 [144][136] fp16 (overlays dump2-dead region; disjoint from h2l) ----
    #pragma unroll
    for (int nt = 0; nt < 9; nt++) {
        int p = nt * 16 + l15;
        f16x4 hv = { (f16)acc9[nt][0], (f16)acc9[nt][1], (f16)acc9[nt][2], (f16)acc9[nt][3] };
        *(f16x4*)&dump3[p * 136 + w * 16 + 4 * agrp] = hv;
    }
    __syncthreads();

    // ---- P6: pool conv3 + bias + prelu + 9-element partial mean ----
    {
        int oc = t >> 2, q = t & 3;
        int qr = q >> 1, qc = q & 1;
        const float a3v = a3[0];
        float cbv = cb3[oc];
        float s = 0.f;
        #pragma unroll
        for (int i = 0; i < 3; i++)
            #pragma unroll
            for (int j = 0; j < 3; j++) {
                int pr = 3 * qr + i, pc = 3 * qc + j;
                int p0 = (2 * pr) * 12 + 2 * pc;
                float mm = fmaxf(fmaxf((float)dump3[p0 * 136 + oc], (float)dump3[(p0 + 1) * 136 + oc]),
                                 fmaxf((float)dump3[(p0 + 12) * 136 + oc], (float)dump3[(p0 + 13) * 136 + oc]));
                float v = mm + cbv;
                v = (v >= 0.0f) ? v : a3v * v;
                s += v;
            }
        ps[t] = s;
    }
    __syncthreads();
    if (t < 128) {
        int cl = cluster[b];
        hb[t] = (ps[4 * t] + ps[4 * t + 1] + ps[4 * t + 2] + ps[4 * t + 3]) * (1.0f / 36.0f)
              + emb2[(size_t)cl * 128 + t] * alpha[0];
    }
    __syncthreads();
    if (t < 64) {
        const float4* wr = (const float4*)(mW1 + t * 128);
        float s = mb1[t];
        #pragma unroll 8
        for (int j = 0; j < 32; j++) {
            float4 wv4 = wr[j];
            s += wv4.x * hb[4 * j] + wv4.y * hb[4 * j + 1] + wv4.z * hb[4 * j + 2] + wv4.w * hb[4 * j + 3];
        }
        float a4v = a4[0];
        t1[t] = (s >= 0.0f) ? s : a4v * s;
    }
    __syncthreads();
    if (t < 32) {
        const float4* wr = (const float4*)(mW2 + t * 64);
        float s = mb2[t];
        #pragma unroll
        for (int j = 0; j < 16; j++) {
            float4 wv4 = wr[j];
            s += wv4.x * t1[4 * j] + wv4.y * t1[4 * j + 1] + wv4.z * t1[4 * j + 2] + wv4.w * t1[4 * j + 3];
        }
        float a5v = a5[0];
        t2[t] = (s >= 0.0f) ? s : a5v * s;
    }
    __syncthreads();
    if (t < 65) {
        const float4* wr = (const float4*)(mW3 + t * 32);
        float s = mb3[t];
        #pragma unroll
        for (int j = 0; j < 8; j++) {
            float4 wv4 = wr[j];
            s += wv4.x * t2[4 * j] + wv4.y * t2[4 * j + 1] + wv4.z * t2[4 * j + 2] + wv4.w * t2[4 * j + 3];
        }
        out[(size_t)b * 65 + t] = s;
    }
}

// ---------------------------------------------------------------------------
extern "C" void kernel_launch(void* const* d_in, const int* in_sizes, int n_in,
                              void* d_out, int out_size, void* d_ws, size_t ws_size,
                              hipStream_t stream)
{
    const float* x         = (const float*)d_in[0];
    const int*   cluster   = (const int*)  d_in[1];
    const float* expert_w  = (const float*)d_in[2];
    const float* cond_b    = (const float*)d_in[3];
    const float* route_emb = (const float*)d_in[4];
    const float* route_W   = (const float*)d_in[5];
    const float* route_b   = (const float*)d_in[6];
    const float* v1  = (const float*)d_in[7];
    const float* g1  = (const float*)d_in[8];
    const float* cb1 = (const float*)d_in[9];
    const float* a1  = (const float*)d_in[10];
    const float* v2  = (const float*)d_in[11];
    const float* g2  = (const float*)d_in[12];
    const float* cb2 = (const float*)d_in[13];
    const float* a2  = (const float*)d_in[14];
    const float* v3  = (const float*)d_in[15];
    const float* g3  = (const float*)d_in[16];
    const float* cb3 = (const float*)d_in[17];
    const float* a3  = (const float*)d_in[18];
    const float* emb2  = (const float*)d_in[19];
    const float* alpha = (const float*)d_in[20];
    const float* mW1 = (const float*)d_in[21];
    const float* mb1 = (const float*)d_in[22];
    const float* a4  = (const float*)d_in[23];
    const float* mW2 = (const float*)d_in[24];
    const float* mb2 = (const float*)d_in[25];
    const float* a5  = (const float*)d_in[26];
    const float* mW3 = (const float*)d_in[27];
    const float* mb3 = (const float*)d_in[28];
    float* ws  = (float*)d_ws;
    float* out = (float*)d_out;

    hipFuncSetAttribute((const void*)k_f1,  hipFuncAttributeMaxDynamicSharedMemorySize, 72448);
    hipFuncSetAttribute((const void*)k_f23, hipFuncAttributeMaxDynamicSharedMemorySize, 114112);

    k_wnorm<<<224, 256, 0, stream>>>(v1, g1, v2, g2, v3, g3, ws);
    k_pool<<<16384, 64, 0, stream>>>(x, ws);
    k_route<<<256, 256, 0, stream>>>(cluster, route_emb, route_W, route_b, expert_w, ws);
    k_f1<<<dim3(6, 256), 512, 72448, stream>>>(x, (const f16*)(ws + OFF_KERN), cond_b,
                                               (const f16*)(ws + OFF_W1), cb1, a1,
                                               (f16*)(ws + OFF_H1));
    k_f23<<<256, 512, 114112, stream>>>((const f16*)(ws + OFF_H1), (const f16*)(ws + OFF_W2),
                                        cb2, a2, (const f16*)(ws + OFF_W3), cb3, a3,
                                        cluster, emb2, alpha,
                                        mW1, mb1, a4, mW2, mb2, a5, mW3, mb3, out);
}

// Round 7
// 121.072 us; speedup vs baseline: 7.7487x; 1.0851x over previous
//
#include <hip/hip_runtime.h>

// Problem constants: B=256, C=64, H=W=48, E=5, DIM=65

typedef _Float16 f16;
typedef f16 f16x8 __attribute__((ext_vector_type(8)));
typedef f16 f16x4 __attribute__((ext_vector_type(4)));
typedef f16 f16x2 __attribute__((ext_vector_type(2)));
typedef __fp16 h16x2 __attribute__((ext_vector_type(2)));
typedef float f32x4 __attribute__((ext_vector_type(4)));

constexpr size_t OFF_POOLED = 0;                       // 256*256 f32
constexpr size_t OFF_KERN   = 65536;                   // 256*4096 f16 (swizzled [b][oc][ic^((oc&7)<<3)])
constexpr size_t OFF_W1     = 65536 + 1048576;         // 9*32*64 f16 swizzled [kk][oc][ic^((oc&7)<<3)]
constexpr size_t OFF_W2     = OFF_W1 + 32*64*12;       // 9*64*32 f16 linear [kk][oc][ic]
constexpr size_t OFF_W3     = OFF_W2 + 64*32*12;       // 9*128*64 f16 linear [kk][oc][ic]
constexpr size_t OFF_H1     = OFF_W3 + 128*64*12;      // 256*576*32 f16 channel-last [b][pos][ic]

__device__ __forceinline__ float sigmoidf_(float z) {
    // rcp is ~1ulp approx; error << fp16 path budget
    return __builtin_amdgcn_rcpf(1.0f + __expf(-z));
}

// v_cvt_pkrtz_f16_f32 with result as _Float16x2 (element conversion is free)
__device__ __forceinline__ f16x2 pkrtz(float a, float b) {
    h16x2 r = __builtin_amdgcn_cvt_pkrtz(a, b);
    f16x2 o; o[0] = (f16)r[0]; o[1] = (f16)r[1];
    return o;
}

// pack 8 floats -> f16x8 via cvt_pkrtz and store swizzled
__device__ __forceinline__ void store_slot8(f16* glds, int row, int sc, int icg, const float* c) {
    f16x2 p0 = pkrtz(c[0], c[1]);
    f16x2 p1 = pkrtz(c[2], c[3]);
    f16x2 p2 = pkrtz(c[4], c[5]);
    f16x2 p3 = pkrtz(c[6], c[7]);
    f16x8 hv = { p0[0], p0[1], p1[0], p1[1], p2[0], p2[1], p3[0], p3[1] };
    *(f16x8*)&glds[(row * 50 + sc) * 64 + ((icg ^ (sc & 7)) << 3)] = hv;
}

// ---------------------------------------------------------------------------
// K0: weight-norm.
//  w1 -> fp16 swizzled [kk][32 oc][64 ic ^ ((oc&7)<<3)]
//  w2 -> fp16 linear  [kk][64 oc][32 ic]
//  w3 -> fp16 linear  [kk][128 oc][64 ic]
// ---------------------------------------------------------------------------
__global__ void k_wnorm(const float* __restrict__ v1, const float* __restrict__ g1,
                        const float* __restrict__ v2, const float* __restrict__ g2,
                        const float* __restrict__ v3, const float* __restrict__ g3,
                        float* __restrict__ ws)
{
    int bo = blockIdx.x;
    const float* v; const float* g; int IC, oc; int which;
    if (bo < 32)       { v = v1; g = g1; oc = bo;      IC = 64; which = 1; }
    else if (bo < 96)  { v = v2; g = g2; oc = bo - 32; IC = 32; which = 2; }
    else               { v = v3; g = g3; oc = bo - 96; IC = 64; which = 3; }
    int n = IC * 9;
    const float* vo = v + (size_t)oc * n;
    float s = 0.0f;
    for (int i = threadIdx.x; i < n; i += 256) { float xv = vo[i]; s += xv * xv; }
    __shared__ float swarp[4];
    __shared__ float sscale;
    int lane = threadIdx.x & 63, wid = threadIdx.x >> 6;
    #pragma unroll
    for (int off = 32; off; off >>= 1) s += __shfl_down(s, off);
    if (lane == 0) swarp[wid] = s;
    __syncthreads();
    if (threadIdx.x == 0) {
        float tsum = swarp[0] + swarp[1] + swarp[2] + swarp[3];
        sscale = g[oc] / sqrtf(tsum);
    }
    __syncthreads();
    float sc = sscale;
    if (which == 1) {
        f16* o1 = (f16*)(ws + OFF_W1);
        for (int i = threadIdx.x; i < n; i += 256) {
            int ic = i / 9, kk = i - ic * 9;
            o1[kk * 2048 + oc * 64 + (ic ^ ((oc & 7) << 3))] = (f16)(vo[i] * sc);
        }
    } else if (which == 2) {
        f16* o2 = (f16*)(ws + OFF_W2);
        for (int i = threadIdx.x; i < n; i += 256) {
            int ic = i / 9, kk = i - ic * 9;
            o2[(kk * 64 + oc) * 32 + ic] = (f16)(vo[i] * sc);
        }
    } else {
        f16* o3 = (f16*)(ws + OFF_W3);
        for (int i = threadIdx.x; i < n; i += 256) {
            int ic = i / 9, kk = i - ic * 9;
            o3[(kk * 128 + oc) * 64 + ic] = (f16)(vo[i] * sc);
        }
    }
}

// ---------------------------------------------------------------------------
// K1: adaptive avg-pool 2x2, one wave per (b,c) slab, float4 loads
// ---------------------------------------------------------------------------
__global__ void __launch_bounds__(64)
k_pool(const float* __restrict__ x, float* __restrict__ ws)
{
    int bc = blockIdx.x;
    int lane = threadIdx.x;
    const float4* p = (const float4*)(x + (size_t)bc * 2304);
    float a0 = 0.f, a1 = 0.f, a2 = 0.f, a3 = 0.f;
    #pragma unroll
    for (int j = 0; j < 9; j++) {
        int i = lane + 64 * j;            // < 576
        int row = i / 12, cg = i - 12 * row;
        float4 v = p[i];
        float s = v.x + v.y + v.z + v.w;
        bool hq = (row >= 24), wq = (cg >= 6);
        a0 += (!hq && !wq) ? s : 0.f;
        a1 += (!hq &&  wq) ? s : 0.f;
        a2 += ( hq && !wq) ? s : 0.f;
        a3 += ( hq &&  wq) ? s : 0.f;
    }
    #pragma unroll
    for (int off = 32; off; off >>= 1) {
        a0 += __shfl_down(a0, off);
        a1 += __shfl_down(a1, off);
        a2 += __shfl_down(a2, off);
        a3 += __shfl_down(a3, off);
    }
    if (lane == 0) {
        int b = bc >> 6, c = bc & 63;
        float* d = ws + OFF_POOLED + (size_t)b * 256 + c * 4;
        d[0] = a0 * (1.0f / 576.0f);
        d[1] = a1 * (1.0f / 576.0f);
        d[2] = a2 * (1.0f / 576.0f);
        d[3] = a3 * (1.0f / 576.0f);
    }
}

// ---------------------------------------------------------------------------
// K2: routing + expert-mixed 1x1 kern -> fp16 swizzled [b][oc][ic^((oc&7)<<3)]
// ---------------------------------------------------------------------------
__global__ void k_route(const int* __restrict__ cluster,
                        const float* __restrict__ route_emb,
                        const float* __restrict__ route_W,
                        const float* __restrict__ route_b,
                        const float* __restrict__ expert_w,
                        float* __restrict__ ws)
{
    int b = blockIdx.x, t = threadIdx.x;
    __shared__ float feat[512];
    __shared__ float rwv[5];
    __shared__ float red[256];
    int cl = cluster[b];
    feat[t]       = ws[OFF_POOLED + (size_t)b * 256 + t];
    feat[256 + t] = route_emb[(size_t)cl * 256 + t];
    __syncthreads();
    float f0 = feat[t], f1 = feat[256 + t];
    for (int e = 0; e < 5; e++) {
        float pv = f0 * route_W[e * 512 + t] + f1 * route_W[e * 512 + 256 + t];
        red[t] = pv;
        __syncthreads();
        if (t < 128) red[t] += red[t + 128];
        __syncthreads();
        if (t < 64) {
            float s = red[t] + red[t + 64];
            #pragma unroll
            for (int off = 32; off; off >>= 1) s += __shfl_down(s, off);
            if (t == 0) rwv[e] = 1.0f / (1.0f + __expf(-(s + route_b[e])));
        }
        __syncthreads();
    }
    float r0 = rwv[0], r1 = rwv[1], r2 = rwv[2], r3 = rwv[3], r4 = rwv[4];
    f16* khg = (f16*)(ws + OFF_KERN);
    for (int j = t; j < 4096; j += 256) {
        int oc = j >> 6, ic = j & 63;
        float kv = r0 * expert_w[j] + r1 * expert_w[4096 + j] +
                   r2 * expert_w[2 * 4096 + j] + r3 * expert_w[3 * 4096 + j] +
                   r4 * expert_w[4 * 4096 + j];
        khg[(size_t)b * 4096 + oc * 64 + (ic ^ ((oc & 7) << 3))] = (f16)kv;
    }
}

// ---------------------------------------------------------------------------
// F1 (MFMA): cc(1x1, A=kern M=oc, B=x N=pos) + gate + conv1 + prelu + pool
// -> h1h fp16 [b][576 pos][32 oc]
// LDS: glds fp16 [10][50][64] (XOR slot swizzle) 0..64000 | kh 64000..72192
//      | cbl 72192..72448.  Total 72448 B -> 2 blocks/CU.
// Overlays (glds dead after P2): hm f16 [8 q][32 oc][26 pp] 0..13312 ;
//                                poolt f16 [96][40] 16384..24064
// ---------------------------------------------------------------------------
__global__ void __launch_bounds__(512, 4)
k_f1(const float* __restrict__ x, const f16* __restrict__ kernH,
     const float* __restrict__ cond_b, const f16* __restrict__ w1H,
     const float* __restrict__ cb1, const float* __restrict__ a1,
     f16* __restrict__ h1h)
{
    extern __shared__ char smem[];
    f16*  glds  = (f16*)smem;                  // 64000 B
    f16*  kh    = (f16*)(smem + 64000);        // 8192 B
    float* cbl  = (float*)(smem + 72192);      // 256 B
    f16*  hm    = (f16*)smem;                  // overlay: 13312 B
    f16*  poolt = (f16*)(smem + 16384);        // overlay: 7680 B

    const int t = threadIdx.x;
    const int tile = blockIdx.x;            // 0..5
    const int b = blockIdx.y;
    const int r0 = tile * 8;
    const int w = t >> 6, l = t & 63;
    const int l15 = l & 15, agrp = l >> 4;

    // ---- P0: stage kern + cond_b, zero border cols, stage x (8x4 reg transpose) ----
    ((uint4*)kh)[t] = ((const uint4*)(kernH + (size_t)b * 4096))[t];
    if (t < 64) cbl[t] = cond_b[t];
    if (t < 160) {                             // cols 0 and 49, all rows/slots
        int row = t >> 4, rem = t & 15;
        int col = (rem >= 8) ? 49 : 0;
        int slot = rem & 7;
        uint4 z = {};
        *(uint4*)&glds[(row * 50 + col) * 64 + slot * 8] = z;
    }
    for (int e = t; e < 960; e += 512) {
        int row = e / 96;                      // 0..9
        int rem = e - row * 96;
        int colg = rem >> 3;                   // 0..11
        int icg = rem & 7;                     // 0..7
        int r_in = r0 - 1 + row;
        float4 va[8];
        if (r_in >= 0 && r_in < 48) {
            const float4* xp = (const float4*)x + ((size_t)(b * 64 + icg * 8)) * 576 + r_in * 12 + colg;
            #pragma unroll
            for (int i = 0; i < 8; i++) va[i] = xp[i * 576];
        } else {
            #pragma unroll
            for (int i = 0; i < 8; i++) va[i] = (float4){0.f, 0.f, 0.f, 0.f};
        }
        float c0[8], c1[8], c2c[8], c3[8];
        #pragma unroll
        for (int i = 0; i < 8; i++) { c0[i] = va[i].x; c1[i] = va[i].y; c2c[i] = va[i].z; c3[i] = va[i].w; }
        int scb = colg * 4 + 1;
        store_slot8(glds, row, scb + 0, icg, c0);
        store_slot8(glds, row, scb + 1, icg, c1);
        store_slot8(glds, row, scb + 2, icg, c2c);
        store_slot8(glds, row, scb + 3, icg, c3);
    }
    __syncthreads();

    // ---- P1: cc 1x1 conv via MFMA (A=kern, B=x) + gate in place (b64 RMW) ----
    {
        const int nt0 = (w < 6) ? 4 * w : 24 + 3 * (w - 6);
        const int NT  = (w < 6) ? 4 : 3;
        f32x4 acc[4][4] = {};
        int srA[4], scA[4];
        #pragma unroll
        for (int j = 0; j < 4; j++) {
            int ntc = nt0 + ((j < NT) ? j : 0);
            int p = ntc * 16 + l15;
            srA[j] = p / 48; scA[j] = p - 48 * srA[j] + 1;
        }
        #pragma unroll
        for (int ks = 0; ks < 2; ks++) {
            f16x8 kfr[4];
            #pragma unroll
            for (int mt = 0; mt < 4; mt++) {
                int oc = mt * 16 + l15;
                kfr[mt] = *(const f16x8*)&kh[oc * 64 + (((ks * 4 + agrp) ^ (oc & 7)) << 3)];
            }
            #pragma unroll
            for (int j = 0; j < 4; j++) {
                f16x8 bfr = *(const f16x8*)&glds[(srA[j] * 50 + scA[j]) * 64 +
                                                 (((ks * 4 + agrp) ^ (scA[j] & 7)) << 3)];
                #pragma unroll
                for (int mt = 0; mt < 4; mt++)
                    acc[mt][j] = __builtin_amdgcn_mfma_f32_16x16x32_f16(kfr[mt], bfr, acc[mt][j], 0, 0, 0);
            }
        }
        // per-thread bias values (f32x4 LDS reads, hoisted)
        f32x4 cbv[4];
        #pragma unroll
        for (int mt = 0; mt < 4; mt++) cbv[mt] = *(const f32x4*)&cbl[mt * 16 + 4 * agrp];
        #pragma unroll
        for (int j = 0; j < 4; j++) {
            if (j < NT) {                            // wave-uniform
                int base = (srA[j] * 50 + scA[j]) * 64;
                int sw8 = (scA[j] & 7) << 3;
                #pragma unroll
                for (int mt = 0; mt < 4; mt++) {
                    int oc0 = mt * 16 + 4 * agrp;    // 4-aligned; XOR hits bits 3..5 only
                    int addr = base + (oc0 ^ sw8);
                    f16x4 xv4 = *(const f16x4*)&glds[addr];
                    float s0 = sigmoidf_(acc[mt][j][0] + cbv[mt][0]);
                    float s1 = sigmoidf_(acc[mt][j][1] + cbv[mt][1]);
                    float s2 = sigmoidf_(acc[mt][j][2] + cbv[mt][2]);
                    float s3 = sigmoidf_(acc[mt][j][3] + cbv[mt][3]);
                    f16x2 slo = pkrtz(s0, s1);
                    f16x2 shi = pkrtz(s2, s3);
                    f16x2 xlo = { xv4[0], xv4[1] };
                    f16x2 xhi = { xv4[2], xv4[3] };
                    f16x2 glo = slo * xlo;           // v_pk_mul_f16
                    f16x2 ghi = shi * xhi;
                    f16x4 g4 = { glo[0], glo[1], ghi[0], ghi[1] };
                    *(f16x4*)&glds[addr] = g4;
                }
            }
        }
    }
    __syncthreads();

    // ---- P2: conv1 3x3 via MFMA (A=x pos, B=w1 oc from GLOBAL) ----
    f32x4 c2[3][2] = {};
    {
        const int q = w;   // out row 0..7
        #pragma unroll
        for (int kt = 0; kt < 18; kt++) {
            const int kk = kt >> 1, hh = kt & 1;
            const int dy = kk / 3, dx = kk - dy * 3;
            f16x8 bfr2[2];
            #pragma unroll
            for (int nt = 0; nt < 2; nt++) {
                int oc = nt * 16 + l15;
                int slot = (hh * 4 + agrp) ^ (oc & 7);
                bfr2[nt] = *(const f16x8*)&w1H[(kk * 32 + oc) * 64 + slot * 8];
            }
            #pragma unroll
            for (int mtl = 0; mtl < 3; mtl++) {
                int sc = mtl * 16 + l15 + dx;
                int slot = (hh * 4 + agrp) ^ (sc & 7);
                f16x8 af = *(const f16x8*)&glds[((q + dy) * 50 + sc) * 64 + slot * 8];
                c2[mtl][0] = __builtin_amdgcn_mfma_f32_16x16x32_f16(af, bfr2[0], c2[mtl][0], 0, 0, 0);
                c2[mtl][1] = __builtin_amdgcn_mfma_f32_16x16x32_f16(af, bfr2[1], c2[mtl][1], 0, 0, 0);
            }
        }
    }
    __syncthreads();   // glds reads done; hm overlays

    // ---- P3: in-register horizontal maxpool + f16 dump hm[q][oc][26] ----
    // D-layout: lane holds positions pcl = mtl*16 + 4*agrp + rr (rr=0..3), oc = nt*16+l15.
    // Pairs (rr0,rr1) and (rr2,rr3) are exactly the horizontal pool pairs.
    {
        const int q = w;
        #pragma unroll
        for (int mtl = 0; mtl < 3; mtl++)
            #pragma unroll
            for (int nt = 0; nt < 2; nt++) {
                float h0 = fmaxf(c2[mtl][nt][0], c2[mtl][nt][1]);
                float h1 = fmaxf(c2[mtl][nt][2], c2[mtl][nt][3]);
                f16x2 hp = pkrtz(h0, h1);
                int oc = nt * 16 + l15;
                int pp = mtl * 8 + 2 * agrp;
                *(f16x2*)&hm[(q * 32 + oc) * 26 + pp] = hp;
            }
    }
    __syncthreads();

    // ---- P4: vertical maxpool + bias + prelu -> poolt fp16 [96 pos][40] ----
    {
        const float av = a1[0];
        #pragma unroll
        for (int k = 0; k < 6; k++) {
            int e = t + 512 * k;                 // 3072 = 96 pos2 x 32 oc
            int oc = e & 31, pos2 = e >> 5;
            int pr = pos2 / 24, pc = pos2 - 24 * pr;
            float v0 = (float)hm[((2 * pr) * 32 + oc) * 26 + pc];
            float v1 = (float)hm[((2 * pr + 1) * 32 + oc) * 26 + pc];
            float v = fmaxf(v0, v1) + cb1[oc];
            v = (v >= 0.0f) ? v : av * v;
            poolt[pos2 * 40 + oc] = (f16)v;
        }
    }
    __syncthreads();

    // ---- P5: coalesced write h1h [b][pos][32] ----
    if (t < 384) {
        int pos2 = t >> 2, slot = t & 3;
        uint4 val = *(const uint4*)&poolt[pos2 * 40 + slot * 8];
        ((uint4*)h1h)[((size_t)b * 576 + tile * 96 + pos2) * 4 + slot] = val;
    }
}

// ---------------------------------------------------------------------------
// F23 (MFMA): conv2+pool + conv3+pool + mean + emb + MLP, one block per sample
// 512 threads / 8 waves (round-3-proven decomposition).
// Weights w2/w3 read from global (L2-hot, no LDS staging).
// LDS: x2[26][26][40h] 0..54080 | h2l[14][14][72h] 82944..111168
//      | ps 111168..113216 | hb 113216..113728 | t1 ..113984 | t2 ..114112
//      dump2 fp16 [576][72] overlays 0..82944 ; dump3 fp16 [144][136] 0..39168
// ---------------------------------------------------------------------------
__global__ void __launch_bounds__(512, 1)
k_f23(const f16* __restrict__ h1h, const f16* __restrict__ w2h,
      const float* __restrict__ cb2, const float* __restrict__ a2,
      const f16* __restrict__ w3h, const float* __restrict__ cb3, const float* __restrict__ a3,
      const int* __restrict__ cluster, const float* __restrict__ emb2, const float* __restrict__ alpha,
      const float* __restrict__ mW1, const float* __restrict__ mb1, const float* __restrict__ a4,
      const float* __restrict__ mW2, const float* __restrict__ mb2, const float* __restrict__ a5,
      const float* __restrict__ mW3, const float* __restrict__ mb3,
      float* __restrict__ out)
{
    extern __shared__ char smem[];
    f16*  x2    = (f16*)smem;
    f16*  h2l   = (f16*)(smem + 82944);
    float* ps   = (float*)(smem + 111168);
    float* hb   = (float*)(smem + 113216);
    float* t1   = (float*)(smem + 113728);
    float* t2   = (float*)(smem + 113984);
    f16*  dump2 = (f16*)smem;
    f16*  dump3 = (f16*)smem;

    const int b = blockIdx.x, t = threadIdx.x;
    const int w = t >> 6, l = t & 63;
    const int l15 = l & 15, agrp = l >> 4;

    // ---- P0: zero borders + stage x2 ----
    for (int e = t; e < 400; e += 512) {          // x2 border: 100 pos x 4 uint4
        int bp = e >> 2, slot = e & 3;
        int r, c;
        if (bp < 26)      { r = 0;  c = bp; }
        else if (bp < 52) { r = 25; c = bp - 26; }
        else if (bp < 76) { r = bp - 52 + 1; c = 0; }
        else              { r = bp - 76 + 1; c = 25; }
        uint4 z = {};
        *(uint4*)&x2[(r * 26 + c) * 40 + slot * 8] = z;
    }
    for (int e = t; e < 416; e += 512) {          // h2l border: 52 pos x 8 uint4
        int bp = e >> 3, slot = e & 7;
        int r, c;
        if (bp < 14)      { r = 0;  c = bp; }
        else if (bp < 28) { r = 13; c = bp - 14; }
        else if (bp < 40) { r = bp - 28 + 1; c = 0; }
        else              { r = bp - 40 + 1; c = 13; }
        uint4 z = {};
        *(uint4*)&h2l[(r * 14 + c) * 72 + slot * 8] = z;
    }
    {
        const uint4* src = (const uint4*)(h1h + (size_t)b * 18432);
        for (int e = t; e < 2304; e += 512) {
            int pos = e >> 2, slot = e & 3;
            int r = pos / 24, c = pos - 24 * r;
            *(uint4*)&x2[((r + 1) * 26 + (c + 1)) * 40 + slot * 8] = src[e];
        }
    }
    __syncthreads();

    // ---- P1: conv2 MFMA (A=w2 global M=oc, B=x2 N=pos) ----
    const int m = w & 3, half = w >> 2;
    f32x4 acc[18];
    {
        f16x8 afr[9];
        #pragma unroll
        for (int kk = 0; kk < 9; kk++)
            afr[kk] = *(const f16x8*)&w2h[(kk * 64 + m * 16 + l15) * 32 + agrp * 8];
        #pragma unroll
        for (int nt = 0; nt < 18; nt++) acc[nt] = (f32x4){0.f, 0.f, 0.f, 0.f};
        constexpr int K2[9] = {0, 40, 80, 26 * 40, 27 * 40, 28 * 40, 52 * 40, 53 * 40, 54 * 40};
        #pragma unroll
        for (int nt = 0; nt < 18; nt++) {
            int p = (half * 18 + nt) * 16 + l15;
            int r = p / 24, c = p - 24 * r;
            int base = (r * 26 + c) * 40 + agrp * 8;
            #pragma unroll
            for (int kk = 0; kk < 9; kk++) {
                f16x8 bfr = *(const f16x8*)&x2[base + K2[kk]];
                acc[nt] = __builtin_amdgcn_mfma_f32_16x16x32_f16(afr[kk], bfr, acc[nt], 0, 0, 0);
            }
        }
    }
    __syncthreads();

    // ---- P2: dump2 [576][72] fp16 ----
    #pragma unroll
    for (int nt = 0; nt < 18; nt++) {
        int p = (half * 18 + nt) * 16 + l15;
        f16x2 d0 = pkrtz(acc[nt][0], acc[nt][1]);
        f16x2 d1 = pkrtz(acc[nt][2], acc[nt][3]);
        f16x4 hv = { d0[0], d0[1], d1[0], d1[1] };
        *(f16x4*)&dump2[p * 72 + m * 16 + 4 * agrp] = hv;
    }
    __syncthreads();

    // ---- P3: pool conv2 + bias + prelu -> h2l [14][14][72] padded ----
    {
        const float a2v = a2[0];
        for (int e = t; e < 9216; e += 512) {
            int oc = e & 63, pos2 = e >> 6;
            int pr = pos2 / 12, pc = pos2 - 12 * pr;
            int p0 = (2 * pr) * 24 + 2 * pc;
            float mm = fmaxf(fmaxf((float)dump2[p0 * 72 + oc], (float)dump2[(p0 + 1) * 72 + oc]),
                             fmaxf((float)dump2[(p0 + 24) * 72 + oc], (float)dump2[(p0 + 25) * 72 + oc]));
            float v = mm + cb2[oc];
            v = (v >= 0.0f) ? v : a2v * v;
            h2l[((pr + 1) * 14 + (pc + 1)) * 72 + oc] = (f16)v;
        }
    }
    __syncthreads();

    // ---- P4: conv3 MFMA (A=w3 global M=oc tile=w, B=h2l N=pos, 9 N-tiles) ----
    f32x4 acc9[9];
    {
        int pb[9];
        #pragma unroll
        for (int nt = 0; nt < 9; nt++) {
            int p = nt * 16 + l15;
            int r = p / 12, c = p - 12 * r;
            pb[nt] = (r * 14 + c) * 72 + agrp * 8;
            acc9[nt] = (f32x4){0.f, 0.f, 0.f, 0.f};
        }
        constexpr int K3[9] = {0, 72, 144, 14 * 72, 15 * 72, 16 * 72, 28 * 72, 29 * 72, 30 * 72};
        #pragma unroll
        for (int kk = 0; kk < 9; kk++) {
            #pragma unroll
            for (int ks = 0; ks < 2; ks++) {
                f16x8 afr = *(const f16x8*)&w3h[(size_t)(kk * 128 + w * 16 + l15) * 64 + ks * 32 + agrp * 8];
                #pragma unroll
                for (int nt = 0; nt < 9; nt++) {
                    f16x8 bfr = *(const f16x8*)&h2l[pb[nt] + ks * 32 + K3[kk]];
                    acc9[nt] = __builtin_amdgcn_mfma_f32_16x16x32_f16(afr, bfr, acc9[nt], 0, 0, 0);
                }
            }
        }
    }
    // ---- P5: dump3 [144][136] fp16 (overlays dump2-dead region; disjoint from h2l) ----
    #pragma unroll
    for (int nt = 0; nt < 9; nt++) {
        int p = nt * 16 + l15;
        f16x2 d0 = pkrtz(acc9[nt][0], acc9[nt][1]);
        f16x2 d1 = pkrtz(acc9[nt][2], acc9[nt][3]);
        f16x4 hv = { d0[0], d0[1], d1[0], d1[1] };
        *(f16x4*)&dump3[p * 136 + w * 16 + 4 * agrp] = hv;
    }
    __syncthreads();

    // ---- P6: pool conv3 + bias + prelu + 9-element partial mean ----
    {
        int oc = t >> 2, q = t & 3;
        int qr = q >> 1, qc = q & 1;
        const float a3v = a3[0];
        float cbv = cb3[oc];
        float s = 0.f;
        #pragma unroll
        for (int i = 0; i < 3; i++)
            #pragma unroll
            for (int j = 0; j < 3; j++) {
                int pr = 3 * qr + i, pc = 3 * qc + j;
                int p0 = (2 * pr) * 12 + 2 * pc;
                float mm = fmaxf(fmaxf((float)dump3[p0 * 136 + oc], (float)dump3[(p0 + 1) * 136 + oc]),
                                 fmaxf((float)dump3[(p0 + 12) * 136 + oc], (float)dump3[(p0 + 13) * 136 + oc]));
                float v = mm + cbv;
                v = (v >= 0.0f) ? v : a3v * v;
                s += v;
            }
        ps[t] = s;
    }
    __syncthreads();
    if (t < 128) {
        int cl = cluster[b];
        hb[t] = (ps[4 * t] + ps[4 * t + 1] + ps[4 * t + 2] + ps[4 * t + 3]) * (1.0f / 36.0f)
              + emb2[(size_t)cl * 128 + t] * alpha[0];
    }
    __syncthreads();
    if (t < 64) {
        const float4* wr = (const float4*)(mW1 + t * 128);
        float s = mb1[t];
        #pragma unroll 8
        for (int j = 0; j < 32; j++) {
            float4 wv4 = wr[j];
            s += wv4.x * hb[4 * j] + wv4.y * hb[4 * j + 1] + wv4.z * hb[4 * j + 2] + wv4.w * hb[4 * j + 3];
        }
        float a4v = a4[0];
        t1[t] = (s >= 0.0f) ? s : a4v * s;
    }
    __syncthreads();
    if (t < 32) {
        const float4* wr = (const float4*)(mW2 + t * 64);
        float s = mb2[t];
        #pragma unroll
        for (int j = 0; j < 16; j++) {
            float4 wv4 = wr[j];
            s += wv4.x * t1[4 * j] + wv4.y * t1[4 * j + 1] + wv4.z * t1[4 * j + 2] + wv4.w * t1[4 * j + 3];
        }
        float a5v = a5[0];
        t2[t] = (s >= 0.0f) ? s : a5v * s;
    }
    __syncthreads();
    if (t < 65) {
        const float4* wr = (const float4*)(mW3 + t * 32);
        float s = mb3[t];
        #pragma unroll
        for (int j = 0; j < 8; j++) {
            float4 wv4 = wr[j];
            s += wv4.x * t2[4 * j] + wv4.y * t2[4 * j + 1] + wv4.z * t2[4 * j + 2] + wv4.w * t2[4 * j + 3];
        }
        out[(size_t)b * 65 + t] = s;
    }
}

// ---------------------------------------------------------------------------
extern "C" void kernel_launch(void* const* d_in, const int* in_sizes, int n_in,
                              void* d_out, int out_size, void* d_ws, size_t ws_size,
                              hipStream_t stream)
{
    const float* x         = (const float*)d_in[0];
    const int*   cluster   = (const int*)  d_in[1];
    const float* expert_w  = (const float*)d_in[2];
    const float* cond_b    = (const float*)d_in[3];
    const float* route_emb = (const float*)d_in[4];
    const float* route_W   = (const float*)d_in[5];
    const float* route_b   = (const float*)d_in[6];
    const float* v1  = (const float*)d_in[7];
    const float* g1  = (const float*)d_in[8];
    const float* cb1 = (const float*)d_in[9];
    const float* a1  = (const float*)d_in[10];
    const float* v2  = (const float*)d_in[11];
    const float* g2  = (const float*)d_in[12];
    const float* cb2 = (const float*)d_in[13];
    const float* a2  = (const float*)d_in[14];
    const float* v3  = (const float*)d_in[15];
    const float* g3  = (const float*)d_in[16];
    const float* cb3 = (const float*)d_in[17];
    const float* a3  = (const float*)d_in[18];
    const float* emb2  = (const float*)d_in[19];
    const float* alpha = (const float*)d_in[20];
    const float* mW1 = (const float*)d_in[21];
    const float* mb1 = (const float*)d_in[22];
    const float* a4  = (const float*)d_in[23];
    const float* mW2 = (const float*)d_in[24];
    const float* mb2 = (const float*)d_in[25];
    const float* a5  = (const float*)d_in[26];
    const float* mW3 = (const float*)d_in[27];
    const float* mb3 = (const float*)d_in[28];
    float* ws  = (float*)d_ws;
    float* out = (float*)d_out;

    hipFuncSetAttribute((const void*)k_f1,  hipFuncAttributeMaxDynamicSharedMemorySize, 72448);
    hipFuncSetAttribute((const void*)k_f23, hipFuncAttributeMaxDynamicSharedMemorySize, 114112);

    k_wnorm<<<224, 256, 0, stream>>>(v1, g1, v2, g2, v3, g3, ws);
    k_pool<<<16384, 64, 0, stream>>>(x, ws);
    k_route<<<256, 256, 0, stream>>>(cluster, route_emb, route_W, route_b, expert_w, ws);
    k_f1<<<dim3(6, 256), 512, 72448, stream>>>(x, (const f16*)(ws + OFF_KERN), cond_b,
                                               (const f16*)(ws + OFF_W1), cb1, a1,
                                               (f16*)(ws + OFF_H1));
    k_f23<<<256, 512, 114112, stream>>>((const f16*)(ws + OFF_H1), (const f16*)(ws + OFF_W2),
                                        cb2, a2, (const f16*)(ws + OFF_W3), cb3, a3,
                                        cluster, emb2, alpha,
                                        mW1, mb1, a4, mW2, mb2, a5, mW3, mb3, out);
}

// Round 8
// 119.045 us; speedup vs baseline: 7.8806x; 1.0170x over previous
//
#include <hip/hip_runtime.h>

// Problem constants: B=256, C=64, H=W=48, E=5, DIM=65

typedef _Float16 f16;
typedef f16 f16x8 __attribute__((ext_vector_type(8)));
typedef f16 f16x4 __attribute__((ext_vector_type(4)));
typedef f16 f16x2 __attribute__((ext_vector_type(2)));
typedef __fp16 h16x2 __attribute__((ext_vector_type(2)));
typedef float f32x4 __attribute__((ext_vector_type(4)));

constexpr size_t OFF_POOLED = 0;                       // 256*256 f32
constexpr size_t OFF_KERN   = 65536;                   // 256*4096 f16 (swizzled [b][oc][ic^((oc&7)<<3)])
constexpr size_t OFF_W1     = 65536 + 1048576;         // 9*32*64 f16 swizzled [kk][oc][ic^((oc&7)<<3)]
constexpr size_t OFF_W2     = OFF_W1 + 32*64*12;       // 9*64*32 f16 linear [kk][oc][ic]
constexpr size_t OFF_W3     = OFF_W2 + 64*32*12;       // 9*128*64 f16 linear [kk][oc][ic]
constexpr size_t OFF_H1     = OFF_W3 + 128*64*12;      // 256*576*32 f16 channel-last [b][pos][ic]

__device__ __forceinline__ float sigmoidf_(float z) {
    return __builtin_amdgcn_rcpf(1.0f + __expf(-z));
}

// v_cvt_pkrtz_f16_f32 with result as _Float16x2 (element conversion is free)
__device__ __forceinline__ f16x2 pkrtz(float a, float b) {
    h16x2 r = __builtin_amdgcn_cvt_pkrtz(a, b);
    f16x2 o; o[0] = (f16)r[0]; o[1] = (f16)r[1];
    return o;
}

// pack 8 floats -> f16x8 via cvt_pkrtz and store swizzled
__device__ __forceinline__ void store_slot8(f16* glds, int row, int sc, int icg, const float* c) {
    f16x2 p0 = pkrtz(c[0], c[1]);
    f16x2 p1 = pkrtz(c[2], c[3]);
    f16x2 p2 = pkrtz(c[4], c[5]);
    f16x2 p3 = pkrtz(c[6], c[7]);
    f16x8 hv = { p0[0], p0[1], p1[0], p1[1], p2[0], p2[1], p3[0], p3[1] };
    *(f16x8*)&glds[(row * 50 + sc) * 64 + ((icg ^ (sc & 7)) << 3)] = hv;
}

// ---------------------------------------------------------------------------
// K_PREP: fused adaptive-avg-pool (blocks 0..16383, one wave per (b,c) slab)
//         + weight-norm (blocks 16384..16607, one wave per oc).
//  w1 -> fp16 swizzled [kk][32 oc][64 ic ^ ((oc&7)<<3)]
//  w2 -> fp16 linear  [kk][64 oc][32 ic]
//  w3 -> fp16 linear  [kk][128 oc][64 ic]
// ---------------------------------------------------------------------------
__global__ void __launch_bounds__(64)
k_prep(const float* __restrict__ x,
       const float* __restrict__ v1, const float* __restrict__ g1,
       const float* __restrict__ v2, const float* __restrict__ g2,
       const float* __restrict__ v3, const float* __restrict__ g3,
       float* __restrict__ ws)
{
    const int blk = blockIdx.x;
    const int lane = threadIdx.x;
    if (blk < 16384) {
        // ---- pool ----
        const float4* p = (const float4*)(x + (size_t)blk * 2304);
        float a0 = 0.f, a1 = 0.f, a2 = 0.f, a3 = 0.f;
        #pragma unroll
        for (int j = 0; j < 9; j++) {
            int i = lane + 64 * j;            // < 576
            int row = i / 12, cg = i - 12 * row;
            float4 v = p[i];
            float s = v.x + v.y + v.z + v.w;
            bool hq = (row >= 24), wq = (cg >= 6);
            a0 += (!hq && !wq) ? s : 0.f;
            a1 += (!hq &&  wq) ? s : 0.f;
            a2 += ( hq && !wq) ? s : 0.f;
            a3 += ( hq &&  wq) ? s : 0.f;
        }
        #pragma unroll
        for (int off = 32; off; off >>= 1) {
            a0 += __shfl_down(a0, off);
            a1 += __shfl_down(a1, off);
            a2 += __shfl_down(a2, off);
            a3 += __shfl_down(a3, off);
        }
        if (lane == 0) {
            int b = blk >> 6, c = blk & 63;
            float* d = ws + OFF_POOLED + (size_t)b * 256 + c * 4;
            d[0] = a0 * (1.0f / 576.0f);
            d[1] = a1 * (1.0f / 576.0f);
            d[2] = a2 * (1.0f / 576.0f);
            d[3] = a3 * (1.0f / 576.0f);
        }
    } else {
        // ---- weight-norm (one wave per output channel) ----
        int bo = blk - 16384;
        const float* v; const float* g; int IC, oc; int which;
        if (bo < 32)       { v = v1; g = g1; oc = bo;      IC = 64; which = 1; }
        else if (bo < 96)  { v = v2; g = g2; oc = bo - 32; IC = 32; which = 2; }
        else               { v = v3; g = g3; oc = bo - 96; IC = 64; which = 3; }
        int n = IC * 9;
        const float* vo = v + (size_t)oc * n;
        float s = 0.0f;
        for (int i = lane; i < n; i += 64) { float xv = vo[i]; s += xv * xv; }
        #pragma unroll
        for (int off = 32; off; off >>= 1) s += __shfl_down(s, off);
        float tot = __shfl(s, 0);
        float sc = g[oc] / sqrtf(tot);
        if (which == 1) {
            f16* o1 = (f16*)(ws + OFF_W1);
            for (int i = lane; i < n; i += 64) {
                int ic = i / 9, kk = i - ic * 9;
                o1[kk * 2048 + oc * 64 + (ic ^ ((oc & 7) << 3))] = (f16)(vo[i] * sc);
            }
        } else if (which == 2) {
            f16* o2 = (f16*)(ws + OFF_W2);
            for (int i = lane; i < n; i += 64) {
                int ic = i / 9, kk = i - ic * 9;
                o2[(kk * 64 + oc) * 32 + ic] = (f16)(vo[i] * sc);
            }
        } else {
            f16* o3 = (f16*)(ws + OFF_W3);
            for (int i = lane; i < n; i += 64) {
                int ic = i / 9, kk = i - ic * 9;
                o3[(kk * 128 + oc) * 64 + ic] = (f16)(vo[i] * sc);
            }
        }
    }
}

// ---------------------------------------------------------------------------
// K2: routing + expert-mixed 1x1 kern -> fp16 swizzled [b][oc][ic^((oc&7)<<3)]
// ---------------------------------------------------------------------------
__global__ void k_route(const int* __restrict__ cluster,
                        const float* __restrict__ route_emb,
                        const float* __restrict__ route_W,
                        const float* __restrict__ route_b,
                        const float* __restrict__ expert_w,
                        float* __restrict__ ws)
{
    int b = blockIdx.x, t = threadIdx.x;
    __shared__ float feat[512];
    __shared__ float rwv[5];
    __shared__ float red[256];
    int cl = cluster[b];
    feat[t]       = ws[OFF_POOLED + (size_t)b * 256 + t];
    feat[256 + t] = route_emb[(size_t)cl * 256 + t];
    __syncthreads();
    float f0 = feat[t], f1 = feat[256 + t];
    for (int e = 0; e < 5; e++) {
        float pv = f0 * route_W[e * 512 + t] + f1 * route_W[e * 512 + 256 + t];
        red[t] = pv;
        __syncthreads();
        if (t < 128) red[t] += red[t + 128];
        __syncthreads();
        if (t < 64) {
            float s = red[t] + red[t + 64];
            #pragma unroll
            for (int off = 32; off; off >>= 1) s += __shfl_down(s, off);
            if (t == 0) rwv[e] = 1.0f / (1.0f + __expf(-(s + route_b[e])));
        }
        __syncthreads();
    }
    float r0 = rwv[0], r1 = rwv[1], r2 = rwv[2], r3 = rwv[3], r4 = rwv[4];
    f16* khg = (f16*)(ws + OFF_KERN);
    for (int j = t; j < 4096; j += 256) {
        int oc = j >> 6, ic = j & 63;
        float kv = r0 * expert_w[j] + r1 * expert_w[4096 + j] +
                   r2 * expert_w[2 * 4096 + j] + r3 * expert_w[3 * 4096 + j] +
                   r4 * expert_w[4 * 4096 + j];
        khg[(size_t)b * 4096 + oc * 64 + (ic ^ ((oc & 7) << 3))] = (f16)kv;
    }
}

// ---------------------------------------------------------------------------
// F1 (MFMA): cc(1x1, A=kern M=oc, B=x N=pos) + gate + conv1 + prelu + pool
// -> h1h fp16 [b][576 pos][32 oc]   (unchanged from round 7 — proven)
// ---------------------------------------------------------------------------
__global__ void __launch_bounds__(512, 4)
k_f1(const float* __restrict__ x, const f16* __restrict__ kernH,
     const float* __restrict__ cond_b, const f16* __restrict__ w1H,
     const float* __restrict__ cb1, const float* __restrict__ a1,
     f16* __restrict__ h1h)
{
    extern __shared__ char smem[];
    f16*  glds  = (f16*)smem;                  // 64000 B
    f16*  kh    = (f16*)(smem + 64000);        // 8192 B
    float* cbl  = (float*)(smem + 72192);      // 256 B
    f16*  hm    = (f16*)smem;                  // overlay: 13312 B
    f16*  poolt = (f16*)(smem + 16384);        // overlay: 7680 B

    const int t = threadIdx.x;
    const int tile = blockIdx.x;            // 0..5
    const int b = blockIdx.y;
    const int r0 = tile * 8;
    const int w = t >> 6, l = t & 63;
    const int l15 = l & 15, agrp = l >> 4;

    // ---- P0: stage kern + cond_b, zero border cols, stage x (8x4 reg transpose) ----
    ((uint4*)kh)[t] = ((const uint4*)(kernH + (size_t)b * 4096))[t];
    if (t < 64) cbl[t] = cond_b[t];
    if (t < 160) {
        int row = t >> 4, rem = t & 15;
        int col = (rem >= 8) ? 49 : 0;
        int slot = rem & 7;
        uint4 z = {};
        *(uint4*)&glds[(row * 50 + col) * 64 + slot * 8] = z;
    }
    for (int e = t; e < 960; e += 512) {
        int row = e / 96;
        int rem = e - row * 96;
        int colg = rem >> 3;
        int icg = rem & 7;
        int r_in = r0 - 1 + row;
        float4 va[8];
        if (r_in >= 0 && r_in < 48) {
            const float4* xp = (const float4*)x + ((size_t)(b * 64 + icg * 8)) * 576 + r_in * 12 + colg;
            #pragma unroll
            for (int i = 0; i < 8; i++) va[i] = xp[i * 576];
        } else {
            #pragma unroll
            for (int i = 0; i < 8; i++) va[i] = (float4){0.f, 0.f, 0.f, 0.f};
        }
        float c0[8], c1[8], c2c[8], c3[8];
        #pragma unroll
        for (int i = 0; i < 8; i++) { c0[i] = va[i].x; c1[i] = va[i].y; c2c[i] = va[i].z; c3[i] = va[i].w; }
        int scb = colg * 4 + 1;
        store_slot8(glds, row, scb + 0, icg, c0);
        store_slot8(glds, row, scb + 1, icg, c1);
        store_slot8(glds, row, scb + 2, icg, c2c);
        store_slot8(glds, row, scb + 3, icg, c3);
    }
    __syncthreads();

    // ---- P1: cc 1x1 conv via MFMA (A=kern, B=x) + gate in place (b64 RMW) ----
    {
        const int nt0 = (w < 6) ? 4 * w : 24 + 3 * (w - 6);
        const int NT  = (w < 6) ? 4 : 3;
        f32x4 acc[4][4] = {};
        int srA[4], scA[4];
        #pragma unroll
        for (int j = 0; j < 4; j++) {
            int ntc = nt0 + ((j < NT) ? j : 0);
            int p = ntc * 16 + l15;
            srA[j] = p / 48; scA[j] = p - 48 * srA[j] + 1;
        }
        #pragma unroll
        for (int ks = 0; ks < 2; ks++) {
            f16x8 kfr[4];
            #pragma unroll
            for (int mt = 0; mt < 4; mt++) {
                int oc = mt * 16 + l15;
                kfr[mt] = *(const f16x8*)&kh[oc * 64 + (((ks * 4 + agrp) ^ (oc & 7)) << 3)];
            }
            #pragma unroll
            for (int j = 0; j < 4; j++) {
                f16x8 bfr = *(const f16x8*)&glds[(srA[j] * 50 + scA[j]) * 64 +
                                                 (((ks * 4 + agrp) ^ (scA[j] & 7)) << 3)];
                #pragma unroll
                for (int mt = 0; mt < 4; mt++)
                    acc[mt][j] = __builtin_amdgcn_mfma_f32_16x16x32_f16(kfr[mt], bfr, acc[mt][j], 0, 0, 0);
            }
        }
        f32x4 cbv[4];
        #pragma unroll
        for (int mt = 0; mt < 4; mt++) cbv[mt] = *(const f32x4*)&cbl[mt * 16 + 4 * agrp];
        #pragma unroll
        for (int j = 0; j < 4; j++) {
            if (j < NT) {
                int base = (srA[j] * 50 + scA[j]) * 64;
                int sw8 = (scA[j] & 7) << 3;
                #pragma unroll
                for (int mt = 0; mt < 4; mt++) {
                    int oc0 = mt * 16 + 4 * agrp;
                    int addr = base + (oc0 ^ sw8);
                    f16x4 xv4 = *(const f16x4*)&glds[addr];
                    float s0 = sigmoidf_(acc[mt][j][0] + cbv[mt][0]);
                    float s1 = sigmoidf_(acc[mt][j][1] + cbv[mt][1]);
                    float s2 = sigmoidf_(acc[mt][j][2] + cbv[mt][2]);
                    float s3 = sigmoidf_(acc[mt][j][3] + cbv[mt][3]);
                    f16x2 slo = pkrtz(s0, s1);
                    f16x2 shi = pkrtz(s2, s3);
                    f16x2 xlo = { xv4[0], xv4[1] };
                    f16x2 xhi = { xv4[2], xv4[3] };
                    f16x2 glo = slo * xlo;
                    f16x2 ghi = shi * xhi;
                    f16x4 g4 = { glo[0], glo[1], ghi[0], ghi[1] };
                    *(f16x4*)&glds[addr] = g4;
                }
            }
        }
    }
    __syncthreads();

    // ---- P2: conv1 3x3 via MFMA (A=x pos, B=w1 oc from GLOBAL) ----
    f32x4 c2[3][2] = {};
    {
        const int q = w;
        #pragma unroll
        for (int kt = 0; kt < 18; kt++) {
            const int kk = kt >> 1, hh = kt & 1;
            const int dy = kk / 3, dx = kk - dy * 3;
            f16x8 bfr2[2];
            #pragma unroll
            for (int nt = 0; nt < 2; nt++) {
                int oc = nt * 16 + l15;
                int slot = (hh * 4 + agrp) ^ (oc & 7);
                bfr2[nt] = *(const f16x8*)&w1H[(kk * 32 + oc) * 64 + slot * 8];
            }
            #pragma unroll
            for (int mtl = 0; mtl < 3; mtl++) {
                int sc = mtl * 16 + l15 + dx;
                int slot = (hh * 4 + agrp) ^ (sc & 7);
                f16x8 af = *(const f16x8*)&glds[((q + dy) * 50 + sc) * 64 + slot * 8];
                c2[mtl][0] = __builtin_amdgcn_mfma_f32_16x16x32_f16(af, bfr2[0], c2[mtl][0], 0, 0, 0);
                c2[mtl][1] = __builtin_amdgcn_mfma_f32_16x16x32_f16(af, bfr2[1], c2[mtl][1], 0, 0, 0);
            }
        }
    }
    __syncthreads();

    // ---- P3: in-register horizontal maxpool + f16 dump hm[q][oc][26] ----
    {
        const int q = w;
        #pragma unroll
        for (int mtl = 0; mtl < 3; mtl++)
            #pragma unroll
            for (int nt = 0; nt < 2; nt++) {
                float h0 = fmaxf(c2[mtl][nt][0], c2[mtl][nt][1]);
                float h1 = fmaxf(c2[mtl][nt][2], c2[mtl][nt][3]);
                f16x2 hp = pkrtz(h0, h1);
                int oc = nt * 16 + l15;
                int pp = mtl * 8 + 2 * agrp;
                *(f16x2*)&hm[(q * 32 + oc) * 26 + pp] = hp;
            }
    }
    __syncthreads();

    // ---- P4: vertical maxpool + bias + prelu -> poolt fp16 [96 pos][40] ----
    {
        const float av = a1[0];
        #pragma unroll
        for (int k = 0; k < 6; k++) {
            int e = t + 512 * k;
            int oc = e & 31, pos2 = e >> 5;
            int pr = pos2 / 24, pc = pos2 - 24 * pr;
            float v0 = (float)hm[((2 * pr) * 32 + oc) * 26 + pc];
            float v1 = (float)hm[((2 * pr + 1) * 32 + oc) * 26 + pc];
            float v = fmaxf(v0, v1) + cb1[oc];
            v = (v >= 0.0f) ? v : av * v;
            poolt[pos2 * 40 + oc] = (f16)v;
        }
    }
    __syncthreads();

    // ---- P5: coalesced write h1h [b][pos][32] ----
    if (t < 384) {
        int pos2 = t >> 2, slot = t & 3;
        uint4 val = *(const uint4*)&poolt[pos2 * 40 + slot * 8];
        ((uint4*)h1h)[((size_t)b * 576 + tile * 96 + pos2) * 4 + slot] = val;
    }
}

// ---------------------------------------------------------------------------
// F23 (MFMA): conv2+pool + conv3+pool + mean + emb + MLP, one block per sample
// 1024 threads / 16 waves.  Coverage (AUDITED, fixes round-4 bug):
//   conv2: m = w&3 (4 oc-tiles -> 64 oc), ng = w>>2 (4 groups x 9 N-tiles = 36)
//   conv3: m8 = w&7 (8 oc-tiles -> 128 oc), ng3 = w>>3 (2 groups, {5,4} = 9)
// Weights w2/w3 read from global (L2-hot).
// LDS layout identical to round 7 (114112 B).
// ---------------------------------------------------------------------------
__global__ void __launch_bounds__(1024, 1)
k_f23(const f16* __restrict__ h1h, const f16* __restrict__ w2h,
      const float* __restrict__ cb2, const float* __restrict__ a2,
      const f16* __restrict__ w3h, const float* __restrict__ cb3, const float* __restrict__ a3,
      const int* __restrict__ cluster, const float* __restrict__ emb2, const float* __restrict__ alpha,
      const float* __restrict__ mW1, const float* __restrict__ mb1, const float* __restrict__ a4,
      const float* __restrict__ mW2, const float* __restrict__ mb2, const float* __restrict__ a5,
      const float* __restrict__ mW3, const float* __restrict__ mb3,
      float* __restrict__ out)
{
    extern __shared__ char smem[];
    f16*  x2    = (f16*)smem;
    f16*  h2l   = (f16*)(smem + 82944);
    float* ps   = (float*)(smem + 111168);
    float* hb   = (float*)(smem + 113216);
    float* t1   = (float*)(smem + 113728);
    float* t2   = (float*)(smem + 113984);
    f16*  dump2 = (f16*)smem;
    f16*  dump3 = (f16*)smem;

    const int b = blockIdx.x, t = threadIdx.x;
    const int w = t >> 6, l = t & 63;
    const int l15 = l & 15, agrp = l >> 4;

    // ---- P0: zero borders + stage x2 ----
    for (int e = t; e < 400; e += 1024) {          // x2 border: 100 pos x 4 uint4
        int bp = e >> 2, slot = e & 3;
        int r, c;
        if (bp < 26)      { r = 0;  c = bp; }
        else if (bp < 52) { r = 25; c = bp - 26; }
        else if (bp < 76) { r = bp - 52 + 1; c = 0; }
        else              { r = bp - 76 + 1; c = 25; }
        uint4 z = {};
        *(uint4*)&x2[(r * 26 + c) * 40 + slot * 8] = z;
    }
    for (int e = t; e < 416; e += 1024) {          // h2l border: 52 pos x 8 uint4
        int bp = e >> 3, slot = e & 7;
        int r, c;
        if (bp < 14)      { r = 0;  c = bp; }
        else if (bp < 28) { r = 13; c = bp - 14; }
        else if (bp < 40) { r = bp - 28 + 1; c = 0; }
        else              { r = bp - 40 + 1; c = 13; }
        uint4 z = {};
        *(uint4*)&h2l[(r * 14 + c) * 72 + slot * 8] = z;
    }
    {
        const uint4* src = (const uint4*)(h1h + (size_t)b * 18432);
        for (int e = t; e < 2304; e += 1024) {
            int pos = e >> 2, slot = e & 3;
            int r = pos / 24, c = pos - 24 * r;
            *(uint4*)&x2[((r + 1) * 26 + (c + 1)) * 40 + slot * 8] = src[e];
        }
    }
    __syncthreads();

    // ---- P1: conv2 MFMA (A=w2 global M=oc, B=x2 N=pos) ----
    // m = w&3 -> oc tile; ng = w>>2 -> N-tiles [9*ng, 9*ng+9)  (36 total: FULL coverage)
    const int m = w & 3, ng = w >> 2;
    f32x4 acc[9];
    {
        f16x8 afr[9];
        #pragma unroll
        for (int kk = 0; kk < 9; kk++)
            afr[kk] = *(const f16x8*)&w2h[(kk * 64 + m * 16 + l15) * 32 + agrp * 8];
        #pragma unroll
        for (int i = 0; i < 9; i++) acc[i] = (f32x4){0.f, 0.f, 0.f, 0.f};
        constexpr int K2[9] = {0, 40, 80, 26 * 40, 27 * 40, 28 * 40, 52 * 40, 53 * 40, 54 * 40};
        #pragma unroll
        for (int i = 0; i < 9; i++) {
            int p = (ng * 9 + i) * 16 + l15;
            int r = p / 24, c = p - 24 * r;
            int base = (r * 26 + c) * 40 + agrp * 8;
            #pragma unroll
            for (int kk = 0; kk < 9; kk++) {
                f16x8 bfr = *(const f16x8*)&x2[base + K2[kk]];
                acc[i] = __builtin_amdgcn_mfma_f32_16x16x32_f16(afr[kk], bfr, acc[i], 0, 0, 0);
            }
        }
    }
    __syncthreads();

    // ---- P2: dump2 [576][72] fp16 ----
    #pragma unroll
    for (int i = 0; i < 9; i++) {
        int p = (ng * 9 + i) * 16 + l15;
        f16x2 d0 = pkrtz(acc[i][0], acc[i][1]);
        f16x2 d1 = pkrtz(acc[i][2], acc[i][3]);
        f16x4 hv = { d0[0], d0[1], d1[0], d1[1] };
        *(f16x4*)&dump2[p * 72 + m * 16 + 4 * agrp] = hv;
    }
    __syncthreads();

    // ---- P3: pool conv2 + bias + prelu -> h2l [14][14][72] padded ----
    {
        const float a2v = a2[0];
        for (int e = t; e < 9216; e += 1024) {
            int oc = e & 63, pos2 = e >> 6;
            int pr = pos2 / 12, pc = pos2 - 12 * pr;
            int p0 = (2 * pr) * 24 + 2 * pc;
            float mm = fmaxf(fmaxf((float)dump2[p0 * 72 + oc], (float)dump2[(p0 + 1) * 72 + oc]),
                             fmaxf((float)dump2[(p0 + 24) * 72 + oc], (float)dump2[(p0 + 25) * 72 + oc]));
            float v = mm + cb2[oc];
            v = (v >= 0.0f) ? v : a2v * v;
            h2l[((pr + 1) * 14 + (pc + 1)) * 72 + oc] = (f16)v;
        }
    }
    __syncthreads();

    // ---- P4: conv3 MFMA (A=w3 global, M-tile m8 = w&7; N-groups ng3 = w>>3 {5,4}) ----
    const int m8 = w & 7, ng3 = w >> 3;
    const int nt0c3 = ng3 * 5;
    const int cnt3  = ng3 ? 4 : 5;
    f32x4 acc3[5];
    {
        int pb[5];
        #pragma unroll
        for (int i = 0; i < 5; i++) {
            int p = (nt0c3 + i) * 16 + l15;
            int r = p / 12, c = p - 12 * r;
            pb[i] = ((r + 1) * 14 + (c + 1)) * 72 + agrp * 8;
            acc3[i] = (f32x4){0.f, 0.f, 0.f, 0.f};
        }
        constexpr int K3[9] = {-15 * 72, -14 * 72, -13 * 72, -72, 0, 72, 13 * 72, 14 * 72, 15 * 72};
        #pragma unroll
        for (int kk = 0; kk < 9; kk++) {
            #pragma unroll
            for (int ks = 0; ks < 2; ks++) {
                f16x8 afr = *(const f16x8*)&w3h[(size_t)(kk * 128 + m8 * 16 + l15) * 64 + ks * 32 + agrp * 8];
                #pragma unroll
                for (int i = 0; i < 5; i++) {
                    if (i < cnt3) {
                        f16x8 bfr = *(const f16x8*)&h2l[pb[i] + ks * 32 + K3[kk]];
                        acc3[i] = __builtin_amdgcn_mfma_f32_16x16x32_f16(afr, bfr, acc3[i], 0, 0, 0);
                    }
                }
            }
        }
    }
    // ---- P5: dump3 [144][136] fp16 (overlays dump2-dead region; disjoint from h2l) ----
    #pragma unroll
    for (int i = 0; i < 5; i++) {
        if (i < cnt3) {
            int p = (nt0c3 + i) * 16 + l15;
            f16x2 d0 = pkrtz(acc3[i][0], acc3[i][1]);
            f16x2 d1 = pkrtz(acc3[i][2], acc3[i][3]);
            f16x4 hv = { d0[0], d0[1], d1[0], d1[1] };
            *(f16x4*)&dump3[p * 136 + m8 * 16 + 4 * agrp] = hv;
        }
    }
    __syncthreads();

    // ---- P6: pool conv3 + bias + prelu + 9-element partial mean ----
    if (t < 512) {
        int oc = t >> 2, q = t & 3;
        int qr = q >> 1, qc = q & 1;
        const float a3v = a3[0];
        float cbv = cb3[oc];
        float s = 0.f;
        #pragma unroll
        for (int i = 0; i < 3; i++)
            #pragma unroll
            for (int j = 0; j < 3; j++) {
                int pr = 3 * qr + i, pc = 3 * qc + j;
                int p0 = (2 * pr) * 12 + 2 * pc;
                float mm = fmaxf(fmaxf((float)dump3[p0 * 136 + oc], (float)dump3[(p0 + 1) * 136 + oc]),
                                 fmaxf((float)dump3[(p0 + 12) * 136 + oc], (float)dump3[(p0 + 13) * 136 + oc]));
                float v = mm + cbv;
                v = (v >= 0.0f) ? v : a3v * v;
                s += v;
            }
        ps[t] = s;
    }
    __syncthreads();
    if (t < 128) {
        int cl = cluster[b];
        hb[t] = (ps[4 * t] + ps[4 * t + 1] + ps[4 * t + 2] + ps[4 * t + 3]) * (1.0f / 36.0f)
              + emb2[(size_t)cl * 128 + t] * alpha[0];
    }
    __syncthreads();
    if (t < 64) {
        const float4* wr = (const float4*)(mW1 + t * 128);
        float s = mb1[t];
        #pragma unroll 8
        for (int j = 0; j < 32; j++) {
            float4 wv4 = wr[j];
            s += wv4.x * hb[4 * j] + wv4.y * hb[4 * j + 1] + wv4.z * hb[4 * j + 2] + wv4.w * hb[4 * j + 3];
        }
        float a4v = a4[0];
        t1[t] = (s >= 0.0f) ? s : a4v * s;
    }
    __syncthreads();
    if (t < 32) {
        const float4* wr = (const float4*)(mW2 + t * 64);
        float s = mb2[t];
        #pragma unroll
        for (int j = 0; j < 16; j++) {
            float4 wv4 = wr[j];
            s += wv4.x * t1[4 * j] + wv4.y * t1[4 * j + 1] + wv4.z * t1[4 * j + 2] + wv4.w * t1[4 * j + 3];
        }
        float a5v = a5[0];
        t2[t] = (s >= 0.0f) ? s : a5v * s;
    }
    __syncthreads();
    if (t < 65) {
        const float4* wr = (const float4*)(mW3 + t * 32);
        float s = mb3[t];
        #pragma unroll
        for (int j = 0; j < 8; j++) {
            float4 wv4 = wr[j];
            s += wv4.x * t2[4 * j] + wv4.y * t2[4 * j + 1] + wv4.z * t2[4 * j + 2] + wv4.w * t2[4 * j + 3];
        }
        out[(size_t)b * 65 + t] = s;
    }
}

// ---------------------------------------------------------------------------
extern "C" void kernel_launch(void* const* d_in, const int* in_sizes, int n_in,
                              void* d_out, int out_size, void* d_ws, size_t ws_size,
                              hipStream_t stream)
{
    const float* x         = (const float*)d_in[0];
    const int*   cluster   = (const int*)  d_in[1];
    const float* expert_w  = (const float*)d_in[2];
    const float* cond_b    = (const float*)d_in[3];
    const float* route_emb = (const float*)d_in[4];
    const float* route_W   = (const float*)d_in[5];
    const float* route_b   = (const float*)d_in[6];
    const float* v1  = (const float*)d_in[7];
    const float* g1  = (const float*)d_in[8];
    const float* cb1 = (const float*)d_in[9];
    const float* a1  = (const float*)d_in[10];
    const float* v2  = (const float*)d_in[11];
    const float* g2  = (const float*)d_in[12];
    const float* cb2 = (const float*)d_in[13];
    const float* a2  = (const float*)d_in[14];
    const float* v3  = (const float*)d_in[15];
    const float* g3  = (const float*)d_in[16];
    const float* cb3 = (const float*)d_in[17];
    const float* a3  = (const float*)d_in[18];
    const float* emb2  = (const float*)d_in[19];
    const float* alpha = (const float*)d_in[20];
    const float* mW1 = (const float*)d_in[21];
    const float* mb1 = (const float*)d_in[22];
    const float* a4  = (const float*)d_in[23];
    const float* mW2 = (const float*)d_in[24];
    const float* mb2 = (const float*)d_in[25];
    const float* a5  = (const float*)d_in[26];
    const float* mW3 = (const float*)d_in[27];
    const float* mb3 = (const float*)d_in[28];
    float* ws  = (float*)d_ws;
    float* out = (float*)d_out;

    hipFuncSetAttribute((const void*)k_f1,  hipFuncAttributeMaxDynamicSharedMemorySize, 72448);
    hipFuncSetAttribute((const void*)k_f23, hipFuncAttributeMaxDynamicSharedMemorySize, 114112);

    k_prep<<<16608, 64, 0, stream>>>(x, v1, g1, v2, g2, v3, g3, ws);
    k_route<<<256, 256, 0, stream>>>(cluster, route_emb, route_W, route_b, expert_w, ws);
    k_f1<<<dim3(6, 256), 512, 72448, stream>>>(x, (const f16*)(ws + OFF_KERN), cond_b,
                                               (const f16*)(ws + OFF_W1), cb1, a1,
                                               (f16*)(ws + OFF_H1));
    k_f23<<<256, 1024, 114112, stream>>>((const f16*)(ws + OFF_H1), (const f16*)(ws + OFF_W2),
                                         cb2, a2, (const f16*)(ws + OFF_W3), cb3, a3,
                                         cluster, emb2, alpha,
                                         mW1, mb1, a4, mW2, mb2, a5, mW3, mb3, out);
}